// Round 1
// baseline (1027.865 us; speedup 1.0000x reference)
//
#include <hip/hip_runtime.h>
#include <math.h>

#define BN_EPS 1e-5f
#define HW_ 128
#define C1_ 32
#define C2_ 64

// ---------------- LDS layout (floats) ----------------
// h tile: 32 ch x 17 rows x 20 (pad for float4-aligned rows)
#define H_ROW   20
#define H_CH    (17 * H_ROW)         // 340
#define H_SIZE  (C1_ * H_CH)         // 10880 floats
// crops tile: 3 ch x 36 rows x 38 (pad for float2 alignment)
#define CR_ROW  38
#define CR_CH   (36 * CR_ROW)        // 1368
#define CR_SIZE (3 * CR_CH)          // 4104
#define W1_SIZE (32 * 28)            // 896 (27 weights padded to 28/ch)
// union region at H_SIZE: stage A/B = crops + w1 (5000 floats);
//                         stage C   = w2 chunk 4ic x 64oc x 12 = 3072 floats
#define UNION_SIZE (CR_SIZE + W1_SIZE)       // 5000
#define BN1_OFF (H_SIZE + UNION_SIZE)        // 15880 (32 ch x {scale,shift})
#define BN2_OFF (BN1_OFF + 64)               // 15944 (64 ch x {scale,shift})
#define LDS_TOTAL (BN2_OFF + 128)            // 16072 floats = 64288 B

__global__ __launch_bounds__(256, 2) void fused_cnn_kernel(
    const float* __restrict__ crops, const float* __restrict__ w1,
    const float* __restrict__ b1, const float* __restrict__ g1,
    const float* __restrict__ be1, const float* __restrict__ m1,
    const float* __restrict__ v1, const float* __restrict__ w2,
    const float* __restrict__ b2, const float* __restrict__ g2,
    const float* __restrict__ be2, const float* __restrict__ m2,
    const float* __restrict__ v2, float* __restrict__ out)
{
    __shared__ __align__(16) float lds[LDS_TOTAL];
    const int tid = threadIdx.x;
    const int b   = blockIdx.x;
    const int img = b >> 4;          // 512 images
    const int t   = b & 15;          // 16 tiles of 4x4 feat
    const int fy0 = (t >> 2) * 4;
    const int fx0 = (t & 3) * 4;
    // crops region needed: conv1 rows [8*fy0-2, 8*fy0+31] -> crops rows +/-1
    const int crop_y0 = 8 * fy0 - 3;
    const int crop_x0 = 8 * fx0 - 3;

    // ---- Stage A: stage crops tile (zero-padded), w1, BN constants ----
    const float* cbase = crops + (size_t)img * (3 * HW_ * HW_);
    for (int idx = tid; idx < 3 * 36 * 36; idx += 256) {
        int ic = idx / 1296;
        int r  = (idx - ic * 1296) / 36;
        int c  = idx - ic * 1296 - r * 36;
        int gr = crop_y0 + r, gc = crop_x0 + c;
        float v = 0.f;
        if (gr >= 0 && gr < HW_ && gc >= 0 && gc < HW_)
            v = cbase[ic * HW_ * HW_ + gr * HW_ + gc];
        lds[H_SIZE + ic * CR_CH + r * CR_ROW + c] = v;
    }
    for (int idx = tid; idx < 32 * 27; idx += 256) {
        int ch = idx / 27, k = idx - ch * 27;
        lds[H_SIZE + CR_SIZE + ch * 28 + k] = w1[idx];
    }
    if (tid < 32) {
        float inv = g1[tid] * rsqrtf(v1[tid] + BN_EPS);
        lds[BN1_OFF + tid * 2]     = inv;
        lds[BN1_OFF + tid * 2 + 1] = b1[tid] * inv + be1[tid] - m1[tid] * inv;
    }
    if (tid >= 64 && tid < 128) {
        int ch = tid - 64;
        float inv = g2[ch] * rsqrtf(v2[ch] + BN_EPS);
        lds[BN2_OFF + ch * 2]     = inv;
        lds[BN2_OFF + ch * 2 + 1] = b2[ch] * inv + be2[ch] - m2[ch] * inv;
    }
    __syncthreads();

    // ---- Stage B: conv1 + bias + BN + ReLU + maxpool2 -> h tile in LDS ----
    // h tile rows/cols (global): [4*fy0-1, 4*fy0+15]; out-of-[0,64) => 0 (conv2 pad)
    {
        const int h_y0 = 4 * fy0 - 1, h_x0 = 4 * fx0 - 1;
        const int ch = tid >> 3;            // 32 ch x 8 threads each
        const int j  = tid & 7;
        // weights for this channel into registers (padded row, float4-aligned)
        float w[28];
        const float* wsrc = &lds[H_SIZE + CR_SIZE + ch * 28];
        #pragma unroll
        for (int q = 0; q < 7; ++q) {
            float4 p = *(const float4*)&wsrc[q * 4];
            w[q * 4] = p.x; w[q * 4 + 1] = p.y; w[q * 4 + 2] = p.z; w[q * 4 + 3] = p.w;
        }
        const float scale = lds[BN1_OFF + ch * 2];
        const float shift = lds[BN1_OFF + ch * 2 + 1];
        for (int p = j; p < 289; p += 8) {
            int hy = p / 17;
            int hx = p - hy * 17;
            int hr = h_y0 + hy, hc = h_x0 + hx;
            float val = 0.f;
            if (hr >= 0 && hr < 64 && hc >= 0 && hc < 64) {
                float c00 = 0.f, c01 = 0.f, c10 = 0.f, c11 = 0.f;
                #pragma unroll
                for (int ic = 0; ic < 3; ++ic) {
                    float a[4][4];
                    const float* src = &lds[H_SIZE + ic * CR_CH + (2 * hy) * CR_ROW + 2 * hx];
                    #pragma unroll
                    for (int r = 0; r < 4; ++r) {
                        float2 p0 = *(const float2*)&src[r * CR_ROW];
                        float2 p1 = *(const float2*)&src[r * CR_ROW + 2];
                        a[r][0] = p0.x; a[r][1] = p0.y; a[r][2] = p1.x; a[r][3] = p1.y;
                    }
                    #pragma unroll
                    for (int ky = 0; ky < 3; ++ky)
                        #pragma unroll
                        for (int kx = 0; kx < 3; ++kx) {
                            float wv = w[ic * 9 + ky * 3 + kx];
                            c00 = fmaf(a[ky][kx],         wv, c00);
                            c01 = fmaf(a[ky][kx + 1],     wv, c01);
                            c10 = fmaf(a[ky + 1][kx],     wv, c10);
                            c11 = fmaf(a[ky + 1][kx + 1], wv, c11);
                        }
                }
                // maxpool then BN+ReLU (BN scale >= 0 => monotone, commutes)
                float m = fmaxf(fmaxf(c00, c01), fmaxf(c10, c11));
                val = fmaxf(fmaf(m, scale, shift), 0.f);
            }
            lds[ch * H_CH + hy * H_ROW + hx] = val;
        }
    }
    __syncthreads();

    // ---- Stage C: conv2(s2) + bias + BN + sigmoid + maxpool2 -> feat ----
    float acc[4][4];   // [ocj][conv pos dy*2+dx]
    #pragma unroll
    for (int i = 0; i < 4; ++i)
        #pragma unroll
        for (int q = 0; q < 4; ++q) acc[i][q] = 0.f;

    const int pos = tid & 15;        // 16 pool positions (4x4 feat tile)
    const int ocg = tid >> 4;        // 16 groups of 4 oc
    const int py = pos >> 2, px = pos & 3;

    for (int ic0 = 0; ic0 < 32; ic0 += 4) {
        __syncthreads();   // protect union region (also separates from stage B)
        // stage w2 chunk: [i(4)][oc(64)][12 padded]
        for (int idx = tid; idx < 4 * 64 * 9; idx += 256) {
            int oc = idx / 36;
            int r  = idx - oc * 36;
            int i  = r / 9, k = r - i * 9;
            lds[H_SIZE + (i * 64 + oc) * 12 + k] = w2[oc * (32 * 9) + (ic0 + i) * 9 + k];
        }
        __syncthreads();
        #pragma unroll
        for (int i = 0; i < 4; ++i) {
            int ic = ic0 + i;
            float hv[5][5];
            const float* hsrc = &lds[ic * H_CH + (4 * py) * H_ROW + 4 * px];
            #pragma unroll
            for (int r = 0; r < 5; ++r) {
                float4 q = *(const float4*)&hsrc[r * H_ROW];
                hv[r][0] = q.x; hv[r][1] = q.y; hv[r][2] = q.z; hv[r][3] = q.w;
                hv[r][4] = hsrc[r * H_ROW + 4];
            }
            #pragma unroll
            for (int ocj = 0; ocj < 4; ++ocj) {
                const float* wp = &lds[H_SIZE + (i * 64 + ocg * 4 + ocj) * 12];
                float w[9];
                float4 qa = *(const float4*)&wp[0];
                float4 qb = *(const float4*)&wp[4];
                w[0] = qa.x; w[1] = qa.y; w[2] = qa.z; w[3] = qa.w;
                w[4] = qb.x; w[5] = qb.y; w[6] = qb.z; w[7] = qb.w;
                w[8] = wp[8];
                #pragma unroll
                for (int dy = 0; dy < 2; ++dy)
                    #pragma unroll
                    for (int dx = 0; dx < 2; ++dx) {
                        float s = acc[ocj][dy * 2 + dx];
                        #pragma unroll
                        for (int ky = 0; ky < 3; ++ky)
                            #pragma unroll
                            for (int kx = 0; kx < 3; ++kx)
                                s = fmaf(hv[2 * dy + ky][2 * dx + kx], w[ky * 3 + kx], s);
                        acc[ocj][dy * 2 + dx] = s;
                    }
            }
        }
    }

    // ---- Epilogue: maxpool (commutes with monotone BN+sigmoid) -> feat ----
    const int fy = fy0 + py, fx = fx0 + px;
    float* outp = out + (size_t)img * (64 * 256);
    #pragma unroll
    for (int ocj = 0; ocj < 4; ++ocj) {
        int oc = ocg * 4 + ocj;
        float m = fmaxf(fmaxf(acc[ocj][0], acc[ocj][1]),
                        fmaxf(acc[ocj][2], acc[ocj][3]));
        float scale = lds[BN2_OFF + oc * 2];
        float shift = lds[BN2_OFF + oc * 2 + 1];
        float z = fmaf(m, scale, shift);
        float sig = 1.f / (1.f + expf(-z));
        outp[oc * 256 + fy * 16 + fx] = sig;
    }
}

__global__ __launch_bounds__(256) void scores_kernel(
    const float* __restrict__ feat, float* __restrict__ scores,
    float* __restrict__ detected)
{
    __shared__ float red[4];
    const int img = blockIdx.x;
    const float4* p = (const float4*)(feat + (size_t)img * 16384);
    float s = 0.f;
    for (int i = threadIdx.x; i < 4096; i += 256) {
        float4 q = p[i];
        s += q.x + q.y + q.z + q.w;
    }
    #pragma unroll
    for (int off = 32; off > 0; off >>= 1)
        s += __shfl_down(s, off, 64);
    if ((threadIdx.x & 63) == 0) red[threadIdx.x >> 6] = s;
    __syncthreads();
    if (threadIdx.x == 0) {
        float mean = (red[0] + red[1] + red[2] + red[3]) * (1.f / 16384.f);
        scores[img] = mean;
        detected[img] = (mean >= 0.55f) ? 1.f : 0.f;
    }
}

extern "C" void kernel_launch(void* const* d_in, const int* in_sizes, int n_in,
                              void* d_out, int out_size, void* d_ws, size_t ws_size,
                              hipStream_t stream) {
    const float* crops = (const float*)d_in[0];
    const float* w1  = (const float*)d_in[1];
    const float* b1  = (const float*)d_in[2];
    const float* g1  = (const float*)d_in[3];
    const float* be1 = (const float*)d_in[4];
    const float* m1  = (const float*)d_in[5];
    const float* v1  = (const float*)d_in[6];
    const float* w2  = (const float*)d_in[7];
    const float* b2  = (const float*)d_in[8];
    const float* g2  = (const float*)d_in[9];
    const float* be2 = (const float*)d_in[10];
    const float* m2  = (const float*)d_in[11];
    const float* v2  = (const float*)d_in[12];
    float* out = (float*)d_out;

    // 512 images x 16 (4x4 feat tiles) = 8192 blocks
    fused_cnn_kernel<<<8192, 256, 0, stream>>>(
        crops, w1, b1, g1, be1, m1, v1, w2, b2, g2, be2, m2, v2, out);

    // feat = out[0 .. 8388608), scores at +8388608, detected at +8389120
    scores_kernel<<<512, 256, 0, stream>>>(out, out + 8388608, out + 8388608 + 512);
}

// Round 2
// 853.545 us; speedup vs baseline: 1.2042x; 1.2042x over previous
//
#include <hip/hip_runtime.h>
#include <math.h>

#define BN_EPS 1e-5f
#define HW_ 128

// ---------------- LDS layout (floats) ----------------
// h tile: 32 ch x 17 rows x 20 (pad for float4-aligned rows)
#define H_ROW   20
#define H_CH    (17 * H_ROW)         // 340
#define H_SIZE  (32 * H_CH)          // 10880 floats
// crops tile: 3 ch x 36 rows x 38 (pad for float2 alignment)
#define CR_ROW  38
#define CR_CH   (36 * CR_ROW)        // 1368
#define CR_SIZE (3 * CR_CH)          // 4104
#define W1_OFF  (H_SIZE + CR_SIZE)
#define UNION_SIZE (CR_SIZE + 32 * 28)       // 5000 (crops + w1 padded 28/ch)
// stage C reuses the union region:
//   w2 chunk: 4 slots x 64 oc x 12 = 3072 floats
//   reduction: 16 x 256 = 4096 floats
#define W2C_OFF H_SIZE
#define RED_OFF H_SIZE
#define BN1_OFF (H_SIZE + UNION_SIZE)        // 15880 (32 ch x {scale,shift})
#define BN2_OFF (BN1_OFF + 64)               // 15944 (64 ch x {scale,shift})
#define LDS_TOTAL (BN2_OFF + 128)            // 16072 floats = 64288 B -> 2 blocks/CU

// block = 512: 2 blocks/CU (LDS-bound) x 8 waves = 16 waves/CU = 4 waves/SIMD
__global__ __launch_bounds__(512, 4) void fused_cnn_kernel(
    const float* __restrict__ crops, const float* __restrict__ w1,
    const float* __restrict__ b1, const float* __restrict__ g1,
    const float* __restrict__ be1, const float* __restrict__ m1,
    const float* __restrict__ v1, const float* __restrict__ w2,
    const float* __restrict__ b2, const float* __restrict__ g2,
    const float* __restrict__ be2, const float* __restrict__ m2,
    const float* __restrict__ v2, float* __restrict__ out)
{
    __shared__ __align__(16) float lds[LDS_TOTAL];
    const int tid = threadIdx.x;
    const int b   = blockIdx.x;
    const int img = b >> 4;          // 512 images
    const int t   = b & 15;          // 16 tiles of 4x4 feat
    const int fy0 = (t >> 2) * 4;
    const int fx0 = (t & 3) * 4;
    const int crop_y0 = 8 * fy0 - 3;
    const int crop_x0 = 8 * fx0 - 3;

    // ---- Stage A: stage crops tile (zero-padded), w1, BN constants ----
    const float* cbase = crops + (size_t)img * (3 * HW_ * HW_);
    for (int idx = tid; idx < 3 * 36 * 36; idx += 512) {
        int ic = idx / 1296;
        int r  = (idx - ic * 1296) / 36;
        int c  = idx - ic * 1296 - r * 36;
        int gr = crop_y0 + r, gc = crop_x0 + c;
        float v = 0.f;
        if (gr >= 0 && gr < HW_ && gc >= 0 && gc < HW_)
            v = cbase[ic * HW_ * HW_ + gr * HW_ + gc];
        lds[H_SIZE + ic * CR_CH + r * CR_ROW + c] = v;
    }
    for (int idx = tid; idx < 32 * 27; idx += 512) {
        int ch = idx / 27, k = idx - ch * 27;
        lds[W1_OFF + ch * 28 + k] = w1[idx];
    }
    if (tid < 32) {
        float inv = g1[tid] * rsqrtf(v1[tid] + BN_EPS);
        lds[BN1_OFF + tid * 2]     = inv;
        lds[BN1_OFF + tid * 2 + 1] = b1[tid] * inv + be1[tid] - m1[tid] * inv;
    }
    if (tid >= 64 && tid < 128) {
        int ch = tid - 64;
        float inv = g2[ch] * rsqrtf(v2[ch] + BN_EPS);
        lds[BN2_OFF + ch * 2]     = inv;
        lds[BN2_OFF + ch * 2 + 1] = b2[ch] * inv + be2[ch] - m2[ch] * inv;
    }
    __syncthreads();

    // ---- Stage B: conv1 + BN + ReLU + maxpool2 -> h tile in LDS ----
    {
        const int h_y0 = 4 * fy0 - 1, h_x0 = 4 * fx0 - 1;
        const int ch = tid >> 4;            // 32 ch x 16 threads each
        const int j  = tid & 15;
        float w[28];
        const float* wsrc = &lds[W1_OFF + ch * 28];
        #pragma unroll
        for (int q = 0; q < 7; ++q) {
            float4 p = *(const float4*)&wsrc[q * 4];
            w[q * 4] = p.x; w[q * 4 + 1] = p.y; w[q * 4 + 2] = p.z; w[q * 4 + 3] = p.w;
        }
        const float scale = lds[BN1_OFF + ch * 2];
        const float shift = lds[BN1_OFF + ch * 2 + 1];
        int hy = 0, hx = j;                 // p = hy*17 + hx, tracked incrementally
        for (int p = j; p < 289; p += 16) {
            int hr = h_y0 + hy, hc = h_x0 + hx;
            float val = 0.f;
            if (hr >= 0 && hr < 64 && hc >= 0 && hc < 64) {
                float c00 = 0.f, c01 = 0.f, c10 = 0.f, c11 = 0.f;
                #pragma unroll
                for (int ic = 0; ic < 3; ++ic) {
                    float a[4][4];
                    const float* src = &lds[H_SIZE + ic * CR_CH + (2 * hy) * CR_ROW + 2 * hx];
                    #pragma unroll
                    for (int r = 0; r < 4; ++r) {
                        float2 p0 = *(const float2*)&src[r * CR_ROW];
                        float2 p1 = *(const float2*)&src[r * CR_ROW + 2];
                        a[r][0] = p0.x; a[r][1] = p0.y; a[r][2] = p1.x; a[r][3] = p1.y;
                    }
                    #pragma unroll
                    for (int ky = 0; ky < 3; ++ky)
                        #pragma unroll
                        for (int kx = 0; kx < 3; ++kx) {
                            float wv = w[ic * 9 + ky * 3 + kx];
                            c00 = fmaf(a[ky][kx],         wv, c00);
                            c01 = fmaf(a[ky][kx + 1],     wv, c01);
                            c10 = fmaf(a[ky + 1][kx],     wv, c10);
                            c11 = fmaf(a[ky + 1][kx + 1], wv, c11);
                        }
                }
                float m = fmaxf(fmaxf(c00, c01), fmaxf(c10, c11));
                val = fmaxf(fmaf(m, scale, shift), 0.f);
            }
            lds[ch * H_CH + hy * H_ROW + hx] = val;
            hx += 16; if (hx >= 17) { hx -= 17; ++hy; }
        }
    }

    // ---- Stage C: conv2(s2) + BN + sigmoid + maxpool2, ic split 2 ways ----
    float acc[4][4];
    #pragma unroll
    for (int i = 0; i < 4; ++i)
        #pragma unroll
        for (int q = 0; q < 4; ++q) acc[i][q] = 0.f;

    const int ic_half = tid >> 8;    // 0: ic 0..15, 1: ic 16..31
    const int pos = tid & 15;        // 16 pool positions (4x4 feat tile)
    const int ocg = (tid >> 4) & 15; // 16 groups of 4 oc
    const int py = pos >> 2, px = pos & 3;

    for (int c = 0; c < 8; ++c) {
        __syncthreads();   // previous chunk / stage B reads of union done
        // stage 4 ic slots: slot 0,1 -> ic 2c+slot ; slot 2,3 -> ic 16+2c+(slot-2)
        for (int idx = tid; idx < 4 * 64 * 9; idx += 512) {
            int slot = idx / 576;
            int r    = idx - slot * 576;
            int oc   = r / 9, k = r - oc * 9;
            int ic   = (slot < 2) ? (2 * c + slot) : (14 + 2 * c + slot);
            lds[W2C_OFF + (slot * 64 + oc) * 12 + k] = w2[oc * 288 + ic * 9 + k];
        }
        __syncthreads();
        #pragma unroll
        for (int i = 0; i < 2; ++i) {
            const int slot = ic_half * 2 + i;
            const int ic   = (ic_half << 4) + 2 * c + i;
            float hv[5][5];
            const float* hsrc = &lds[ic * H_CH + (4 * py) * H_ROW + 4 * px];
            #pragma unroll
            for (int r = 0; r < 5; ++r) {
                float4 q = *(const float4*)&hsrc[r * H_ROW];
                hv[r][0] = q.x; hv[r][1] = q.y; hv[r][2] = q.z; hv[r][3] = q.w;
                hv[r][4] = hsrc[r * H_ROW + 4];
            }
            #pragma unroll
            for (int ocj = 0; ocj < 4; ++ocj) {
                const float* wp = &lds[W2C_OFF + (slot * 64 + ocg * 4 + ocj) * 12];
                float w[9];
                float4 qa = *(const float4*)&wp[0];
                float4 qb = *(const float4*)&wp[4];
                w[0] = qa.x; w[1] = qa.y; w[2] = qa.z; w[3] = qa.w;
                w[4] = qb.x; w[5] = qb.y; w[6] = qb.z; w[7] = qb.w;
                w[8] = wp[8];
                #pragma unroll
                for (int dy = 0; dy < 2; ++dy)
                    #pragma unroll
                    for (int dx = 0; dx < 2; ++dx) {
                        float s = acc[ocj][dy * 2 + dx];
                        #pragma unroll
                        for (int ky = 0; ky < 3; ++ky)
                            #pragma unroll
                            for (int kx = 0; kx < 3; ++kx)
                                s = fmaf(hv[2 * dy + ky][2 * dx + kx], w[ky * 3 + kx], s);
                        acc[ocj][dy * 2 + dx] = s;
                    }
            }
        }
    }

    // ---- Reduce the two ic-halves (conflict-free: consecutive lanes/banks) ----
    __syncthreads();
    if (ic_half) {
        int tt = tid & 255;
        #pragma unroll
        for (int jj = 0; jj < 16; ++jj)
            lds[RED_OFF + jj * 256 + tt] = acc[jj >> 2][jj & 3];
    }
    __syncthreads();
    if (!ic_half) {
        #pragma unroll
        for (int jj = 0; jj < 16; ++jj)
            acc[jj >> 2][jj & 3] += lds[RED_OFF + jj * 256 + tid];

        // ---- Epilogue: maxpool (commutes with monotone BN+sigmoid) -> feat ----
        const int fy = fy0 + py, fx = fx0 + px;
        float* outp = out + (size_t)img * (64 * 256);
        #pragma unroll
        for (int ocj = 0; ocj < 4; ++ocj) {
            int oc = ocg * 4 + ocj;
            float m = fmaxf(fmaxf(acc[ocj][0], acc[ocj][1]),
                            fmaxf(acc[ocj][2], acc[ocj][3]));
            float scale = lds[BN2_OFF + oc * 2];
            float shift = lds[BN2_OFF + oc * 2 + 1];
            float z = fmaf(m, scale, shift);
            float sig = 1.f / (1.f + expf(-z));
            outp[oc * 256 + fy * 16 + fx] = sig;
        }
    }
}

__global__ __launch_bounds__(256) void scores_kernel(
    const float* __restrict__ feat, float* __restrict__ scores,
    float* __restrict__ detected)
{
    __shared__ float red[4];
    const int img = blockIdx.x;
    const float4* p = (const float4*)(feat + (size_t)img * 16384);
    float s = 0.f;
    for (int i = threadIdx.x; i < 4096; i += 256) {
        float4 q = p[i];
        s += q.x + q.y + q.z + q.w;
    }
    #pragma unroll
    for (int off = 32; off > 0; off >>= 1)
        s += __shfl_down(s, off, 64);
    if ((threadIdx.x & 63) == 0) red[threadIdx.x >> 6] = s;
    __syncthreads();
    if (threadIdx.x == 0) {
        float mean = (red[0] + red[1] + red[2] + red[3]) * (1.f / 16384.f);
        scores[img] = mean;
        detected[img] = (mean >= 0.55f) ? 1.f : 0.f;
    }
}

extern "C" void kernel_launch(void* const* d_in, const int* in_sizes, int n_in,
                              void* d_out, int out_size, void* d_ws, size_t ws_size,
                              hipStream_t stream) {
    (void)in_sizes; (void)n_in; (void)out_size; (void)d_ws; (void)ws_size;
    const float* crops = (const float*)d_in[0];
    const float* w1  = (const float*)d_in[1];
    const float* b1  = (const float*)d_in[2];
    const float* g1  = (const float*)d_in[3];
    const float* be1 = (const float*)d_in[4];
    const float* m1  = (const float*)d_in[5];
    const float* v1  = (const float*)d_in[6];
    const float* w2  = (const float*)d_in[7];
    const float* b2  = (const float*)d_in[8];
    const float* g2  = (const float*)d_in[9];
    const float* be2 = (const float*)d_in[10];
    const float* m2  = (const float*)d_in[11];
    const float* v2  = (const float*)d_in[12];
    float* out = (float*)d_out;

    // 512 images x 16 (4x4 feat tiles) = 8192 blocks x 512 threads
    fused_cnn_kernel<<<8192, 512, 0, stream>>>(
        crops, w1, b1, g1, be1, m1, v1, w2, b2, g2, be2, m2, v2, out);

    scores_kernel<<<512, 256, 0, stream>>>(out, out + 8388608, out + 8388608 + 512);
}

// Round 4
// 478.944 us; speedup vs baseline: 2.1461x; 1.7821x over previous
//
#include <hip/hip_runtime.h>
#include <math.h>

#define BN_EPS 1e-5f
#define HW_ 128

typedef unsigned short u16_t;
typedef unsigned int u32_t;

typedef __bf16 bf16x8 __attribute__((ext_vector_type(8)));
typedef float f32x4 __attribute__((ext_vector_type(4)));
typedef u32_t u32x4 __attribute__((ext_vector_type(4)));
typedef u32x4 u32x4_ma __attribute__((may_alias));   // TBAA-proof 16B LDS loads
typedef u32_t u32_ma __attribute__((may_alias));

static __device__ __forceinline__ u16_t f2bf(float f) {
    u32_t u = __float_as_uint(f);
    return (u16_t)((u + 0x7FFFu + ((u >> 16) & 1u)) >> 16);
}
static __device__ __forceinline__ u32_t packbf(float a, float b) {
    return (u32_t)f2bf(a) | ((u32_t)f2bf(b) << 16);
}
static __device__ __forceinline__ bf16x8 ld_frag_u32(const u32_t* p) {
    union { u32x4 u; bf16x8 f; } x;
    x.u = *(const u32x4_ma*)p;
    return x.f;
}
static __device__ __forceinline__ bf16x8 ld_frag_u16(const u16_t* p) {
    union { u32x4 u; bf16x8 f; } x;
    x.u = *(const u32x4_ma*)p;
    return x.f;
}

// LDS budget (bytes): crops 15984 + h 18496 + AS 37888 + w1f 2048 + bn 768
//                   = 75184  -> 2 blocks/CU (150.4 KB of 160 KB)
#define CR_ROW 37
#define CR_CH  (36 * CR_ROW)   // 1332 floats per input channel

// block = 512 threads (8 waves); 2 blocks/CU -> 4 waves/SIMD
__global__ __launch_bounds__(512, 4) void fused_cnn_kernel(
    const float* __restrict__ crops, const float* __restrict__ w1,
    const float* __restrict__ b1, const float* __restrict__ g1,
    const float* __restrict__ be1, const float* __restrict__ m1,
    const float* __restrict__ v1, const float* __restrict__ w2,
    const float* __restrict__ b2, const float* __restrict__ g2,
    const float* __restrict__ be2, const float* __restrict__ m2,
    const float* __restrict__ v2, float* __restrict__ out)
{
    __shared__ __align__(16) float  cropsS[3 * CR_CH];     // [ic][36][37]
    __shared__ __align__(16) u16_t  hS[289 * 32];          // pooled h, [pos][ic] bf16
    __shared__ __align__(16) u32_t  AS[592 * 16];          // im2col chunk / w2r union
    __shared__ __align__(16) u32_t  w1fS[512];             // conv1 B-frags [2][64][4]
    __shared__ float bn1S[64];                             // 32 ch x {scale,shift}
    __shared__ float bn2S[128];                            // 64 ch x {scale,shift}

    const int tid  = threadIdx.x;
    const int wave = tid >> 6;
    const int lane = tid & 63;
    const int quad = lane >> 4;
    const int r    = lane & 15;

    const int blk = blockIdx.x;
    const int img = blk >> 4;
    const int t   = blk & 15;
    const int fy0 = (t >> 2) * 4;
    const int fx0 = (t & 3) * 4;
    const int crop_y0 = 8 * fy0 - 3;
    const int crop_x0 = 8 * fx0 - 3;

    // ================= Phase 0: stage crops, w1 frags, BN tables ==========
    // defensive zero of hS (coverage insurance; also conv2 zero-pad base)
    for (int idx = tid; idx < (289 * 32) / 2; idx += 512)
        ((u32_ma*)hS)[idx] = 0u;

    const float* cbase = crops + (size_t)img * (3 * HW_ * HW_);
    for (int idx = tid; idx < 3 * 36 * 36; idx += 512) {
        int ic  = idx / 1296;
        int rem = idx - ic * 1296;
        int rr  = rem / 36;
        int cc  = rem - rr * 36;
        int gr = crop_y0 + rr, gc = crop_x0 + cc;
        float v = 0.f;
        if (gr >= 0 && gr < HW_ && gc >= 0 && gc < HW_)
            v = cbase[ic * HW_ * HW_ + gr * HW_ + gc];
        cropsS[ic * CR_CH + rr * CR_ROW + cc] = v;
    }
    {   // w1 B-frag: value = w1[oc = nt*16+(ln&15)][k = (ln>>4)*8 + 2*j2 + {0,1}]
        int nt   = tid >> 8;            // 0..1
        int ln   = (tid >> 2) & 63;
        int j2   = tid & 3;
        int k0   = ((ln >> 4) << 3) + 2 * j2;
        int oc   = (nt << 4) + (ln & 15);
        float a0 = (k0     < 27) ? w1[oc * 27 + k0]     : 0.f;
        float a1 = (k0 + 1 < 27) ? w1[oc * 27 + k0 + 1] : 0.f;
        w1fS[(nt * 64 + ln) * 4 + j2] = packbf(a0, a1);
    }
    if (tid < 32) {
        float inv = g1[tid] * rsqrtf(v1[tid] + BN_EPS);
        bn1S[tid * 2]     = inv;
        bn1S[tid * 2 + 1] = b1[tid] * inv + be1[tid] - m1[tid] * inv;
    }
    if (tid >= 64 && tid < 128) {
        int ch = tid - 64;
        float inv = g2[ch] * rsqrtf(v2[ch] + BN_EPS);
        bn2S[ch * 2]     = inv;
        bn2S[ch * 2 + 1] = b2[ch] * inv + be2[ch] - m2[ch] * inv;
    }
    __syncthreads();

    // im2col thread-constant decode: kp = tid&15 fixed; k = 2kp, 2kp+1
    const int kp = tid & 15;
    const int k0 = 2 * kp, k1 = 2 * kp + 1;
    const int ic0 = k0 / 9, t0 = k0 - 9 * ic0, ky0 = t0 / 3, kx0 = t0 - 3 * ky0;
    const int ic1 = k1 / 9, t1 = k1 - 9 * ic1, ky1 = t1 / 3, kx1 = t1 - 3 * ky1;
    const bool z0 = (k0 < 27), z1 = (k1 < 27);
    const int base0 = min(ic0, 2) * CR_CH + ky0 * CR_ROW + kx0;
    const int base1 = min(ic1, 2) * CR_CH + ky1 * CR_ROW + kx1;

    // conv1 per-wave constants
    const int nt1   = wave & 1;          // conv1 n-tile (oc group)
    const int oc1   = nt1 * 16 + r;
    const float s1  = bn1S[oc1 * 2];
    const float sh1 = bn1S[oc1 * 2 + 1];
    const bf16x8 bf1 = ld_frag_u32(&w1fS[(nt1 * 64 + lane) * 4]);
    const f32x4 zero4 = {0.f, 0.f, 0.f, 0.f};

    // ================= Phase 1: conv1 (2 chunks of 37 m-tiles) ============
    #pragma unroll 1
    for (int c = 0; c < 2; ++c) {
        // ---- im2col: A[pos_local][32] bf16, morton pos = pgrp*4 + sub ----
        for (int i = 0; i < 19; ++i) {
            int pos_local = (tid >> 4) + 32 * i;
            if (pos_local < 592) {
                int gp   = c * 592 + pos_local;
                int pgrp = gp >> 2, sub = gp & 3;
                int y2 = (pgrp * 241) >> 12; y2 = min(y2, 16);
                int x2 = min(pgrp - y2 * 17, 16);
                int ym = 2 * y2 + (sub >> 1);
                int xm = 2 * x2 + (sub & 1);
                int rowoff = ym * CR_ROW + xm;
                float v0  = z0 ? cropsS[base0 + rowoff] : 0.f;
                float v1v = z1 ? cropsS[base1 + rowoff] : 0.f;
                AS[pos_local * 16 + kp] = packbf(v0, v1v);
            }
        }
        __syncthreads();
        // ---- MFMA + in-register maxpool + BN/ReLU -> hS ----
        for (int i = 0; i < 10; ++i) {
            int tt = wave + 8 * i;
            if (tt < 74) {
                int ml = tt >> 1;    // local m-tile (nt1 = wave&1 == tt&1)
                bf16x8 af = ld_frag_u32(&AS[(ml * 16 + r) * 16 + quad * 4]);
                f32x4 d = __builtin_amdgcn_mfma_f32_16x16x32_bf16(af, bf1, zero4, 0, 0, 0);
                int p = (c * 37 + ml) * 4 + quad;    // pooled pos
                if (p < 289) {
                    float m4 = fmaxf(fmaxf(d[0], d[1]), fmaxf(d[2], d[3]));
                    float val = fmaxf(fmaf(m4, s1, sh1), 0.f);
                    // zero outside the global pooled-h range (conv2 zero-pad)
                    int y2p = (p * 241) >> 12;
                    int x2p = p - y2p * 17;
                    int gy2 = 4 * fy0 - 1 + y2p;
                    int gx2 = 4 * fx0 - 1 + x2p;
                    if (gy2 < 0 || gy2 > 63 || gx2 < 0 || gx2 > 63) val = 0.f;
                    hS[p * 32 + oc1] = f2bf(val);
                }
            }
        }
        __syncthreads();
    }

    // ================= Phase 2a: stage w2 reordered [tap][oc][ic] bf16 ====
    for (int i = 0; i < 18; ++i) {
        int idx = tid + 512 * i;              // < 9216
        int icp = idx & 15;
        int oc  = (idx >> 4) & 63;
        int tap = idx >> 10;
        float a0 = w2[oc * 288 + (2 * icp)     * 9 + tap];
        float a1 = w2[oc * 288 + (2 * icp + 1) * 9 + tap];
        AS[(tap * 64 + oc) * 16 + icp] = packbf(a0, a1);
    }
    __syncthreads();

    // ================= Phase 2b: conv2 MFMA, pool via shfl, write feat ====
    {
        const int mt  = wave >> 1;            // oc tile (4)
        const int nt0 = (wave & 1) * 2;       // pos tiles nt0, nt0+1
        float s2v[4], sh2v[4];
        #pragma unroll
        for (int reg = 0; reg < 4; ++reg) {
            int oc = mt * 16 + quad * 4 + reg;
            s2v[reg]  = bn2S[oc * 2];
            sh2v[reg] = bn2S[oc * 2 + 1];
        }
        f32x4 acc0 = zero4, acc1 = zero4;
        const int rhi = r >> 3, rlo = r & 7;
        #pragma unroll
        for (int s = 0; s < 9; ++s) {
            const int ky = s / 3, kx = s - 3 * (s / 3);
            bf16x8 af = ld_frag_u32(&AS[(s * 64 + mt * 16 + r) * 16 + quad * 4]);
            int hrow = 4 * nt0 + 2 * rhi + ky;
            int hcol = 2 * rlo + kx;
            const u16_t* hb = &hS[(hrow * 17 + hcol) * 32 + quad * 8];
            bf16x8 b0  = ld_frag_u16(hb);
            bf16x8 b1f = ld_frag_u16(hb + 4 * 17 * 32);
            acc0 = __builtin_amdgcn_mfma_f32_16x16x32_bf16(af, b0,  acc0, 0, 0, 0);
            acc1 = __builtin_amdgcn_mfma_f32_16x16x32_bf16(af, b1f, acc1, 0, 0, 0);
        }
        // pooled partners: pos^1 (lane r^1) and pos^8 (lane r^8)
        float* outp = out + (size_t)img * 16384;
        const bool active = ((r & 9) == 0);   // r in {0,2,4,6}
        const int fxl = r >> 1;               // 0..3 for active lanes
        #pragma unroll
        for (int half = 0; half < 2; ++half) {
            f32x4 a = half ? acc1 : acc0;
            int fy = fy0 + nt0 + half;
            #pragma unroll
            for (int reg = 0; reg < 4; ++reg) {
                float v = a[reg];
                float m = fmaxf(v, __shfl_xor(v, 1));
                m = fmaxf(m, __shfl_xor(m, 8));
                float z = fmaf(m, s2v[reg], sh2v[reg]);
                float sig = 1.f / (1.f + expf(-z));
                if (active) {
                    int oc = mt * 16 + quad * 4 + reg;
                    outp[oc * 256 + fy * 16 + fx0 + fxl] = sig;
                }
            }
        }
    }
}

__global__ __launch_bounds__(256) void scores_kernel(
    const float* __restrict__ feat, float* __restrict__ scores,
    float* __restrict__ detected)
{
    __shared__ float red[4];
    const int img = blockIdx.x;
    const float4* p = (const float4*)(feat + (size_t)img * 16384);
    float s = 0.f;
    for (int i = threadIdx.x; i < 4096; i += 256) {
        float4 q = p[i];
        s += q.x + q.y + q.z + q.w;
    }
    #pragma unroll
    for (int off = 32; off > 0; off >>= 1)
        s += __shfl_down(s, off, 64);
    if ((threadIdx.x & 63) == 0) red[threadIdx.x >> 6] = s;
    __syncthreads();
    if (threadIdx.x == 0) {
        float mean = (red[0] + red[1] + red[2] + red[3]) * (1.f / 16384.f);
        scores[img] = mean;
        detected[img] = (mean >= 0.55f) ? 1.f : 0.f;
    }
}

extern "C" void kernel_launch(void* const* d_in, const int* in_sizes, int n_in,
                              void* d_out, int out_size, void* d_ws, size_t ws_size,
                              hipStream_t stream) {
    (void)in_sizes; (void)n_in; (void)out_size; (void)d_ws; (void)ws_size;
    const float* crops = (const float*)d_in[0];
    const float* w1  = (const float*)d_in[1];
    const float* b1  = (const float*)d_in[2];
    const float* g1  = (const float*)d_in[3];
    const float* be1 = (const float*)d_in[4];
    const float* m1  = (const float*)d_in[5];
    const float* v1  = (const float*)d_in[6];
    const float* w2  = (const float*)d_in[7];
    const float* b2  = (const float*)d_in[8];
    const float* g2  = (const float*)d_in[9];
    const float* be2 = (const float*)d_in[10];
    const float* m2  = (const float*)d_in[11];
    const float* v2  = (const float*)d_in[12];
    float* out = (float*)d_out;

    fused_cnn_kernel<<<8192, 512, 0, stream>>>(
        crops, w1, b1, g1, be1, m1, v1, w2, b2, g2, be2, m2, v2, out);

    scores_kernel<<<512, 256, 0, stream>>>(out, out + 8388608, out + 8388608 + 512);
}

// Round 5
// 346.588 us; speedup vs baseline: 2.9657x; 1.3819x over previous
//
#include <hip/hip_runtime.h>
#include <math.h>

#define BN_EPS 1e-5f
#define HW_ 128

typedef unsigned short u16_t;
typedef unsigned int u32_t;

typedef __bf16 bf16x8 __attribute__((ext_vector_type(8)));
typedef float f32x4 __attribute__((ext_vector_type(4)));
typedef u32_t u32x4 __attribute__((ext_vector_type(4)));
typedef u32x4 u32x4_ma __attribute__((may_alias));
typedef u32_t u32_ma __attribute__((may_alias));
typedef u16_t u16_ma __attribute__((may_alias));

static __device__ __forceinline__ u16_t f2bf(float f) {
    u32_t u = __float_as_uint(f);
    return (u16_t)((u + 0x7FFFu + ((u >> 16) & 1u)) >> 16);
}
static __device__ __forceinline__ u32_t packbf(float a, float b) {
    return (u32_t)f2bf(a) | ((u32_t)f2bf(b) << 16);
}
static __device__ __forceinline__ bf16x8 ld_frag16(const u16_t* p) {
    union { u32x4 u; bf16x8 f; } x;
    x.u = *(const u32x4_ma*)p;
    return x.f;
}
static __device__ __forceinline__ bf16x8 ld_frag32(const u32_t* p) {
    union { u32x4 u; bf16x8 f; } x;
    x.u = *(const u32x4_ma*)p;
    return x.f;
}
static __device__ __forceinline__ bf16x8 asbf(u32x4 u) {
    union { u32x4 u; bf16x8 f; } x;
    x.u = u;
    return x.f;
}

// crops tile: 36 rows x 36 cols x 8 ch (ch3..7 = 0), bf16, row pitch 304 u16
#define CI_PITCH 304
#define CI_U32   (36 * CI_PITCH / 2)      // 5472 u32 = 21888 B
// union: crops tile (phase 0-1)  |  w2r half [9 tap][32 oc][32 ic] u16 = 4608 u32
// LDS total: 21888 + 18496 (hS) + 512 (bn2) = 40896 B -> up to 4 blocks/CU

__global__ __launch_bounds__(512, 6) void fused_cnn_kernel(
    const float* __restrict__ crops, const float* __restrict__ w1,
    const float* __restrict__ b1, const float* __restrict__ g1,
    const float* __restrict__ be1, const float* __restrict__ m1,
    const float* __restrict__ v1, const float* __restrict__ w2,
    const float* __restrict__ b2, const float* __restrict__ g2,
    const float* __restrict__ be2, const float* __restrict__ m2,
    const float* __restrict__ v2, float* __restrict__ out)
{
    __shared__ __align__(16) u32_t uniS[CI_U32];   // crops-interleaved ∪ w2r-half
    __shared__ __align__(16) u16_t hS[289 * 32];   // pooled h, [pgrp][32 ic] bf16
    __shared__ float bn2S[128];

    const int tid  = threadIdx.x;
    const int wave = tid >> 6;
    const int lane = tid & 63;
    const int quad = lane >> 4;
    const int r    = lane & 15;

    const int blk = blockIdx.x;
    const int img = blk >> 4;
    const int t   = blk & 15;
    const int fy0 = (t >> 2) * 4;
    const int fx0 = (t & 3) * 4;
    const int crop_y0 = 8 * fy0 - 3;
    const int crop_x0 = 8 * fx0 - 3;

    // ---- Phase 0a: zero crops region (pads/ch3..7), bn2 table ----
    for (int i = tid; i < CI_U32; i += 512) uniS[i] = 0u;
    if (tid >= 64 && tid < 128) {
        int ch = tid - 64;
        float inv = g2[ch] * rsqrtf(v2[ch] + BN_EPS);
        bn2S[ch * 2]     = inv;
        bn2S[ch * 2 + 1] = b2[ch] * inv + be2[ch] - m2[ch] * inv;
    }

    // ---- w1 B-frags + bn1 constants in registers (global reads, no LDS) ----
    // B[k=quad*8+j][n=r]: kx=quad (<3), ic=j (<3); value w1[oc][ic][ky][kx]
    u32x4 wf[2][3];
    #pragma unroll
    for (int h = 0; h < 2; ++h)
        #pragma unroll
        for (int ky = 0; ky < 3; ++ky) {
            float wa = 0.f, wb = 0.f, wc = 0.f;
            if (quad < 3) {
                const float* wp = w1 + (h * 16 + r) * 27 + ky * 3 + quad;
                wa = wp[0]; wb = wp[9]; wc = wp[18];
            }
            u32x4 f;
            f[0] = packbf(wa, wb); f[1] = packbf(wc, 0.f); f[2] = 0u; f[3] = 0u;
            wf[h][ky] = f;
        }
    float s1v[2], sh1v[2];
    #pragma unroll
    for (int h = 0; h < 2; ++h) {
        int oc = h * 16 + r;
        float inv = g1[oc] * rsqrtf(v1[oc] + BN_EPS);
        s1v[h]  = inv;
        sh1v[h] = b1[oc] * inv + be1[oc] - m1[oc] * inv;
    }
    __syncthreads();   // zero complete before u16 fills land in same words

    // ---- Phase 0b: stage crops channel-interleaved bf16 ----
    u16_ma* cropsI = (u16_ma*)uniS;
    const float* cbase = crops + (size_t)img * (3 * HW_ * HW_);
    for (int idx = tid; idx < 3 * 36 * 36; idx += 512) {
        int ic  = idx / 1296;
        int rem = idx - ic * 1296;
        int rr  = rem / 36;
        int cc  = rem - rr * 36;
        int gr = crop_y0 + rr, gc = crop_x0 + cc;
        float v = 0.f;
        if (gr >= 0 && gr < HW_ && gc >= 0 && gc < HW_)
            v = cbase[ic * (HW_ * HW_) + gr * HW_ + gc];
        cropsI[rr * CI_PITCH + cc * 8 + ic] = f2bf(v);
    }
    __syncthreads();

    const f32x4 zero4 = {0.f, 0.f, 0.f, 0.f};

    // ---- Phase 1: conv1 via direct-A MFMA (no im2col), pool in-register ----
    // 73 position-tiles of 16 (4 pool-groups x 4 morton subs)
    for (int tt = wave; tt < 73; tt += 8) {
        int pA  = tt * 4 + (r >> 2);                  // A-side pooled group
        int gyA = (pA * 241) >> 12; gyA = min(gyA, 16);
        int gxA = min(pA - gyA * 17, 16);
        int cy  = 2 * gyA + ((r >> 1) & 1);           // conv-out row in tile
        int cx  = 2 * gxA + (r & 1);
        int base = cy * CI_PITCH + cx * 8 + quad * 8;
        bf16x8 a0 = ld_frag16((const u16_t*)&cropsI[base]);
        bf16x8 a1 = ld_frag16((const u16_t*)&cropsI[base + CI_PITCH]);
        bf16x8 a2 = ld_frag16((const u16_t*)&cropsI[base + 2 * CI_PITCH]);

        int pD  = tt * 4 + quad;                      // D-side pooled group
        int gyD = (pD * 241) >> 12;
        int gxD = pD - gyD * 17;
        int y2p = 4 * fy0 - 1 + gyD, x2p = 4 * fx0 - 1 + gxD;
        bool inb = (pD < 289);
        bool nz  = (y2p >= 0 && y2p < 64 && x2p >= 0 && x2p < 64);
        #pragma unroll
        for (int h = 0; h < 2; ++h) {
            f32x4 d = __builtin_amdgcn_mfma_f32_16x16x32_bf16(a0, asbf(wf[h][0]), zero4, 0, 0, 0);
            d = __builtin_amdgcn_mfma_f32_16x16x32_bf16(a1, asbf(wf[h][1]), d, 0, 0, 0);
            d = __builtin_amdgcn_mfma_f32_16x16x32_bf16(a2, asbf(wf[h][2]), d, 0, 0, 0);
            if (inb) {
                float m4 = fmaxf(fmaxf(d[0], d[1]), fmaxf(d[2], d[3]));
                float val = fmaxf(fmaf(m4, s1v[h], sh1v[h]), 0.f);
                if (!nz) val = 0.f;
                hS[pD * 32 + h * 16 + r] = f2bf(val);
            }
        }
    }
    __syncthreads();   // hS complete; cropsI region now dead

    // ---- Phase 2: conv2 in two oc-halves (w2r-half unions with cropsI) ----
    float* outp = out + (size_t)img * 16384;
    #pragma unroll 1
    for (int H = 0; H < 2; ++H) {
        // stage w2r half: [tap][32 ocl][32 ic] bf16 (u32-packed pairs)
        for (int i2 = 0; i2 < 9; ++i2) {
            int idx = tid + 512 * i2;                 // < 4608
            int icp = idx & 15;
            int ocl = (idx >> 4) & 31;
            int tap = idx >> 9;
            const float* wp = w2 + (H * 32 + ocl) * 288 + tap;
            float a0v = wp[(2 * icp) * 9];
            float a1v = wp[(2 * icp + 1) * 9];
            uniS[(tap * 32 + ocl) * 16 + icp] = packbf(a0v, a1v);
        }
        __syncthreads();

        const int mt  = wave & 1;                     // oc-tile within half
        const int nt0 = wave >> 1;                    // conv-pos row-pair 0..3
        const int rhi = r >> 3, rlo = r & 7;
        f32x4 acc = zero4;
        #pragma unroll
        for (int s = 0; s < 9; ++s) {
            const int ky = s / 3, kx = s - 3 * (s / 3);
            bf16x8 af = ld_frag32(&uniS[(s * 32 + mt * 16 + r) * 16 + quad * 4]);
            int hrow = 4 * nt0 + 2 * rhi + ky;
            int hcol = 2 * rlo + kx;
            bf16x8 bx = ld_frag16(&hS[(hrow * 17 + hcol) * 32 + quad * 8]);
            acc = __builtin_amdgcn_mfma_f32_16x16x32_bf16(af, bx, acc, 0, 0, 0);
        }
        // epilogue: maxpool via shfl (partners r^1, r^8), BN + sigmoid
        const bool active = ((r & 9) == 0);           // r in {0,2,4,6}
        const int fxl = r >> 1;
        const int fy  = fy0 + nt0;
        #pragma unroll
        for (int reg = 0; reg < 4; ++reg) {
            int oc = H * 32 + mt * 16 + quad * 4 + reg;
            float v = acc[reg];
            float m = fmaxf(v, __shfl_xor(v, 1));
            m = fmaxf(m, __shfl_xor(m, 8));
            float z = fmaf(m, bn2S[oc * 2], bn2S[oc * 2 + 1]);
            float sig = 1.f / (1.f + expf(-z));
            if (active) outp[oc * 256 + fy * 16 + fx0 + fxl] = sig;
        }
        if (H == 0) __syncthreads();   // before re-staging w2r half 1
    }
}

__global__ __launch_bounds__(256) void scores_kernel(
    const float* __restrict__ feat, float* __restrict__ scores,
    float* __restrict__ detected)
{
    __shared__ float red[4];
    const int img = blockIdx.x;
    const float4* p = (const float4*)(feat + (size_t)img * 16384);
    float s = 0.f;
    for (int i = threadIdx.x; i < 4096; i += 256) {
        float4 q = p[i];
        s += q.x + q.y + q.z + q.w;
    }
    #pragma unroll
    for (int off = 32; off > 0; off >>= 1)
        s += __shfl_down(s, off, 64);
    if ((threadIdx.x & 63) == 0) red[threadIdx.x >> 6] = s;
    __syncthreads();
    if (threadIdx.x == 0) {
        float mean = (red[0] + red[1] + red[2] + red[3]) * (1.f / 16384.f);
        scores[img] = mean;
        detected[img] = (mean >= 0.55f) ? 1.f : 0.f;
    }
}

extern "C" void kernel_launch(void* const* d_in, const int* in_sizes, int n_in,
                              void* d_out, int out_size, void* d_ws, size_t ws_size,
                              hipStream_t stream) {
    (void)in_sizes; (void)n_in; (void)out_size; (void)d_ws; (void)ws_size;
    const float* crops = (const float*)d_in[0];
    const float* w1  = (const float*)d_in[1];
    const float* b1  = (const float*)d_in[2];
    const float* g1  = (const float*)d_in[3];
    const float* be1 = (const float*)d_in[4];
    const float* m1  = (const float*)d_in[5];
    const float* v1  = (const float*)d_in[6];
    const float* w2  = (const float*)d_in[7];
    const float* b2  = (const float*)d_in[8];
    const float* g2  = (const float*)d_in[9];
    const float* be2 = (const float*)d_in[10];
    const float* m2  = (const float*)d_in[11];
    const float* v2  = (const float*)d_in[12];
    float* out = (float*)d_out;

    fused_cnn_kernel<<<8192, 512, 0, stream>>>(
        crops, w1, b1, g1, be1, m1, v1, w2, b2, g2, be2, m2, v2, out);

    scores_kernel<<<512, 256, 0, stream>>>(out, out + 8388608, out + 8388608 + 512);
}

// Round 6
// 312.016 us; speedup vs baseline: 3.2943x; 1.1108x over previous
//
#include <hip/hip_runtime.h>
#include <math.h>

#define BN_EPS 1e-5f
#define HW_ 128

typedef unsigned short u16_t;
typedef unsigned int u32_t;

typedef __bf16 bf16x8 __attribute__((ext_vector_type(8)));
typedef float f32x4 __attribute__((ext_vector_type(4)));
typedef float f32x16 __attribute__((ext_vector_type(16)));
typedef u32_t u32x4 __attribute__((ext_vector_type(4)));
typedef u32x4 u32x4_ma __attribute__((may_alias));
typedef u16_t u16_ma __attribute__((may_alias));

static __device__ __forceinline__ u16_t f2bf(float f) {
    u32_t u = __float_as_uint(f);
    return (u16_t)((u + 0x7FFFu + ((u >> 16) & 1u)) >> 16);
}
static __device__ __forceinline__ u32_t packbf(float a, float b) {
    return (u32_t)f2bf(a) | ((u32_t)f2bf(b) << 16);
}
static __device__ __forceinline__ bf16x8 ld_frag16(const u16_t* p) {
    union { u32x4 u; bf16x8 f; } x;
    x.u = *(const u32x4_ma*)p;
    return x.f;
}
static __device__ __forceinline__ bf16x8 ld_frag32(const u32_t* p) {
    union { u32x4 u; bf16x8 f; } x;
    x.u = *(const u32x4_ma*)p;
    return x.f;
}
static __device__ __forceinline__ bf16x8 asbf(u32x4 u) {
    union { u32x4 u; bf16x8 f; } x;
    x.u = u;
    return x.f;
}

// crops tile: 36 rows x 36 cols x 8 ch (ch3..7 = 0), bf16, row pitch 304 u16
#define CI_PITCH 304
#define CI_U32   (36 * 152)               // 5472 u32 = 21888 B
// union: crops tile (phase 0-1) | w2r half [9 tap][32 oc][16 u32] = 4608 u32
// LDS total ~ 21888 + 18496 (hS) + 512 (bn2) + 32 (red) = 40928 B -> 4 blocks/CU

__global__ __launch_bounds__(512, 8) void fused_cnn_kernel(
    const float* __restrict__ crops, const float* __restrict__ w1,
    const float* __restrict__ b1, const float* __restrict__ g1,
    const float* __restrict__ be1, const float* __restrict__ m1,
    const float* __restrict__ v1, const float* __restrict__ w2,
    const float* __restrict__ b2, const float* __restrict__ g2,
    const float* __restrict__ be2, const float* __restrict__ m2,
    const float* __restrict__ v2, float* __restrict__ out,
    float* __restrict__ wsum)
{
    __shared__ __align__(16) u32_t uniS[CI_U32];   // crops-interleaved ∪ w2r-half
    __shared__ __align__(16) u16_t hS[289 * 32];   // pooled h, [pgrp][32 ic] bf16
    __shared__ float bn2S[128];
    __shared__ float redS[8];

    const int tid  = threadIdx.x;
    const int wave = tid >> 6;
    const int lane = tid & 63;
    const int quad = lane >> 4;
    const int r    = lane & 15;
    const int n32  = lane & 31;      // 32-wide index for 32x32 MFMA
    const int halfk = lane >> 5;     // k-half for 32x32 MFMA

    const int blk = blockIdx.x;
    const int img = blk >> 4;
    const int t   = blk & 15;
    const int fy0 = (t >> 2) * 4;
    const int fx0 = (t & 3) * 4;
    const int crop_y0 = 8 * fy0 - 3;
    const int crop_x0 = 8 * fx0 - 3;

    // ---- Phase 0: stage crops (full 8-ch b128 writes, zeros included) ----
    if (tid >= 64 && tid < 128) {
        int ch = tid - 64;
        float inv = g2[ch] * rsqrtf(v2[ch] + BN_EPS);
        bn2S[ch * 2]     = inv;
        bn2S[ch * 2 + 1] = b2[ch] * inv + be2[ch] - m2[ch] * inv;
    }
    const float* cbase = crops + (size_t)img * (3 * HW_ * HW_);
    #pragma unroll
    for (int i = 0; i < 3; ++i) {
        int idx = tid + 512 * i;
        if (idx < 1296) {
            int rr = (idx * 1821) >> 16;          // idx/36, exact for idx<1296
            int cc = idx - rr * 36;
            int gr = crop_y0 + rr, gc = crop_x0 + cc;
            float v0 = 0.f, v1v = 0.f, v2v = 0.f;
            if (gr >= 0 && gr < HW_ && gc >= 0 && gc < HW_) {
                const float* p = cbase + gr * HW_ + gc;
                v0  = p[0];
                v1v = p[HW_ * HW_];
                v2v = p[2 * HW_ * HW_];
            }
            u32x4 w;
            w[0] = packbf(v0, v1v); w[1] = packbf(v2v, 0.f); w[2] = 0u; w[3] = 0u;
            *(u32x4_ma*)&uniS[rr * 152 + cc * 4] = w;
        }
    }

    // ---- conv1 B-frags (w1) + bn1 in registers ----
    // B[k = halfk*8+j][n=oc=n32]: k-step s covers pixels {2s, 2s+1}, ic=j (<3)
    u32x4 wf[5];
    #pragma unroll
    for (int s = 0; s < 5; ++s) {
        int p = 2 * s + halfk;
        bool valid = (p <= 8);
        const float* wp = w1 + n32 * 27 + (valid ? p : 8);
        float wa = valid ? wp[0]  : 0.f;
        float wb = valid ? wp[9]  : 0.f;
        float wc = valid ? wp[18] : 0.f;
        u32x4 f;
        f[0] = packbf(wa, wb); f[1] = packbf(wc, 0.f); f[2] = 0u; f[3] = 0u;
        wf[s] = f;
    }
    const float inv1 = g1[n32] * rsqrtf(v1[n32] + BN_EPS);
    const float sh1  = b1[n32] * inv1 + be1[n32] - m1[n32] * inv1;
    __syncthreads();

    // ---- Phase 1: conv1 via 32x32x16 MFMA, pool in-register -> hS ----
    // per-lane per-K-step pixel offsets (u16): h0 p=0,2,4,6,8; h1 p=1,3,5,7,(8)
    const int off0 = halfk ? 8          : 0;
    const int off1 = halfk ? 304        : 16;
    const int off2 = halfk ? 304 + 16   : 304 + 8;
    const int off3 = halfk ? 608 + 8    : 608;
    const int off4 = 608 + 16;
    const u16_t* cropsI = (const u16_t*)uniS;

    #pragma unroll 1
    for (int tt = wave; tt < 37; tt += 8) {
        int gA = n32 >> 2, sub = n32 & 3;
        int pA = tt * 8 + gA;
        int gy = (pA * 241) >> 12; gy = min(gy, 16);
        int gx = min(pA - gy * 17, 16);
        int cy = 2 * gy + (sub >> 1), cx = 2 * gx + (sub & 1);
        const u16_t* base = cropsI + cy * CI_PITCH + cx * 8;

        bf16x8 a0 = ld_frag16(base + off0);
        bf16x8 a1 = ld_frag16(base + off1);
        bf16x8 a2 = ld_frag16(base + off2);
        bf16x8 a3 = ld_frag16(base + off3);
        bf16x8 a4 = ld_frag16(base + off4);

        f32x16 acc = {0.f,0.f,0.f,0.f,0.f,0.f,0.f,0.f,
                      0.f,0.f,0.f,0.f,0.f,0.f,0.f,0.f};
        acc = __builtin_amdgcn_mfma_f32_32x32x16_bf16(a0, asbf(wf[0]), acc, 0, 0, 0);
        acc = __builtin_amdgcn_mfma_f32_32x32x16_bf16(a1, asbf(wf[1]), acc, 0, 0, 0);
        acc = __builtin_amdgcn_mfma_f32_32x32x16_bf16(a2, asbf(wf[2]), acc, 0, 0, 0);
        acc = __builtin_amdgcn_mfma_f32_32x32x16_bf16(a3, asbf(wf[3]), acc, 0, 0, 0);
        acc = __builtin_amdgcn_mfma_f32_32x32x16_bf16(a4, asbf(wf[4]), acc, 0, 0, 0);

        // D rows for reg-quad q: m = 8q + 4*halfk + (reg&3) -> pool group 2q+halfk
        #pragma unroll
        for (int q = 0; q < 4; ++q) {
            int pD = tt * 8 + 2 * q + halfk;
            float m4 = fmaxf(fmaxf(acc[4 * q], acc[4 * q + 1]),
                             fmaxf(acc[4 * q + 2], acc[4 * q + 3]));
            float val = fmaxf(fmaf(m4, inv1, sh1), 0.f);
            int gyD = (pD * 241) >> 12;
            int gxD = pD - gyD * 17;
            int y2 = 4 * fy0 - 1 + gyD, x2 = 4 * fx0 - 1 + gxD;
            if (y2 < 0 || y2 > 63 || x2 < 0 || x2 > 63) val = 0.f;
            if (pD < 289) hS[pD * 32 + n32] = f2bf(val);
        }
    }
    __syncthreads();   // hS complete; cropsI region now dead

    // ---- Phase 2: conv2 (16x16x32) in two oc-halves; score partial sum ----
    float* outp = out + (size_t)img * 16384;
    const f32x4 zero4 = {0.f, 0.f, 0.f, 0.f};
    float ssum = 0.f;
    #pragma unroll 1
    for (int H = 0; H < 2; ++H) {
        // stage w2r half: [tap][32 ocl][32 ic] bf16 (u32-packed ic pairs)
        for (int i2 = 0; i2 < 9; ++i2) {
            int idx = tid + 512 * i2;                 // < 4608
            int icp = idx & 15;
            int ocl = (idx >> 4) & 31;
            int tap = idx >> 9;
            const float* wp = w2 + (H * 32 + ocl) * 288 + tap;
            float a0v = wp[(2 * icp) * 9];
            float a1v = wp[(2 * icp + 1) * 9];
            uniS[(tap * 32 + ocl) * 16 + icp] = packbf(a0v, a1v);
        }
        __syncthreads();

        const int mt  = wave & 1;                     // oc-tile within half
        const int nt0 = wave >> 1;                    // conv-pos row-pair 0..3
        const int rhi = r >> 3, rlo = r & 7;
        f32x4 acc = zero4;
        #pragma unroll
        for (int s = 0; s < 9; ++s) {
            const int ky = s / 3, kx = s - 3 * (s / 3);
            bf16x8 af = ld_frag32(&uniS[(s * 32 + mt * 16 + r) * 16 + quad * 4]);
            int hrow = 4 * nt0 + 2 * rhi + ky;
            int hcol = 2 * rlo + kx;
            bf16x8 bx = ld_frag16(&hS[(hrow * 17 + hcol) * 32 + quad * 8]);
            acc = __builtin_amdgcn_mfma_f32_16x16x32_bf16(af, bx, acc, 0, 0, 0);
        }
        // epilogue: maxpool via shfl (partners r^1, r^8), BN + sigmoid
        const bool active = ((r & 9) == 0);           // r in {0,2,4,6}
        const int fxl = r >> 1;
        const int fy  = fy0 + nt0;
        #pragma unroll
        for (int reg = 0; reg < 4; ++reg) {
            int oc = H * 32 + mt * 16 + quad * 4 + reg;
            float v = acc[reg];
            float m = fmaxf(v, __shfl_xor(v, 1));
            m = fmaxf(m, __shfl_xor(m, 8));
            float z = fmaf(m, bn2S[oc * 2], bn2S[oc * 2 + 1]);
            float sig = 1.f / (1.f + expf(-z));
            if (active) {
                outp[oc * 256 + fy * 16 + fx0 + fxl] = sig;
                ssum += sig;
            }
        }
        if (H == 0) __syncthreads();   // before re-staging w2r half 1
    }

    // ---- block score partial -> global atomic ----
    #pragma unroll
    for (int off = 32; off > 0; off >>= 1)
        ssum += __shfl_xor(ssum, off);
    if (lane == 0) redS[wave] = ssum;
    __syncthreads();
    if (tid == 0) {
        float bs = 0.f;
        #pragma unroll
        for (int w = 0; w < 8; ++w) bs += redS[w];
        atomicAdd(&wsum[img], bs);
    }
}

__global__ void zero_scores_kernel(float* __restrict__ ws) {
    ws[threadIdx.x] = 0.f;
}

__global__ void finalize_kernel(const float* __restrict__ ws,
                                float* __restrict__ scores,
                                float* __restrict__ detected) {
    int i = threadIdx.x;
    float mean = ws[i] * (1.f / 16384.f);
    scores[i] = mean;
    detected[i] = (mean >= 0.55f) ? 1.f : 0.f;
}

extern "C" void kernel_launch(void* const* d_in, const int* in_sizes, int n_in,
                              void* d_out, int out_size, void* d_ws, size_t ws_size,
                              hipStream_t stream) {
    (void)in_sizes; (void)n_in; (void)out_size; (void)ws_size;
    const float* crops = (const float*)d_in[0];
    const float* w1  = (const float*)d_in[1];
    const float* b1  = (const float*)d_in[2];
    const float* g1  = (const float*)d_in[3];
    const float* be1 = (const float*)d_in[4];
    const float* m1  = (const float*)d_in[5];
    const float* v1  = (const float*)d_in[6];
    const float* w2  = (const float*)d_in[7];
    const float* b2  = (const float*)d_in[8];
    const float* g2  = (const float*)d_in[9];
    const float* be2 = (const float*)d_in[10];
    const float* m2  = (const float*)d_in[11];
    const float* v2  = (const float*)d_in[12];
    float* out = (float*)d_out;
    float* ws  = (float*)d_ws;

    zero_scores_kernel<<<1, 512, 0, stream>>>(ws);
    fused_cnn_kernel<<<8192, 512, 0, stream>>>(
        crops, w1, b1, g1, be1, m1, v1, w2, b2, g2, be2, m2, v2, out, ws);
    finalize_kernel<<<1, 512, 0, stream>>>(ws, out + 8388608, out + 8388608 + 512);
}

// Round 7
// 309.653 us; speedup vs baseline: 3.3194x; 1.0076x over previous
//
#include <hip/hip_runtime.h>
#include <math.h>

#define BN_EPS 1e-5f
#define HW_ 128

typedef unsigned short u16_t;
typedef unsigned int u32_t;

typedef __bf16 bf16x8 __attribute__((ext_vector_type(8)));
typedef float f32x4 __attribute__((ext_vector_type(4)));
typedef float f32x16 __attribute__((ext_vector_type(16)));
typedef u32_t u32x4 __attribute__((ext_vector_type(4)));
typedef u32x4 u32x4_ma __attribute__((may_alias));
typedef u16_t u16_ma __attribute__((may_alias));

static __device__ __forceinline__ u16_t f2bf(float f) {
    u32_t u = __float_as_uint(f);
    return (u16_t)((u + 0x7FFFu + ((u >> 16) & 1u)) >> 16);
}
static __device__ __forceinline__ u32_t packbf(float a, float b) {
    return (u32_t)f2bf(a) | ((u32_t)f2bf(b) << 16);
}
static __device__ __forceinline__ bf16x8 ld_frag16(const u16_t* p) {
    union { u32x4 u; bf16x8 f; } x;
    x.u = *(const u32x4_ma*)p;
    return x.f;
}
static __device__ __forceinline__ bf16x8 ld_frag32(const u32_t* p) {
    union { u32x4 u; bf16x8 f; } x;
    x.u = *(const u32x4_ma*)p;
    return x.f;
}
static __device__ __forceinline__ bf16x8 asbf(u32x4 u) {
    union { u32x4 u; bf16x8 f; } x;
    x.u = u;
    return x.f;
}

// ---- d_ws table layout (u32 units) ----
#define WSUM_OFF 0        // 512 floats (per-image sigmoid sums)
#define W2R_OFF  512      // 9216 u32: [H][tap][32 ocl][16 icp] packed bf16 pairs
#define WF_OFF   9728     // 5*64 uint4 = 1280 u32: conv1 B-frags [s][lane]
#define PT_OFF   11008    // 1184 u32: conv1 A base offsets [tt][n32]
#define BN1_OFF  12192    // 64 u32: 32 x {inv, shift}
#define BN2_OFF  12256    // 128 u32: 64 x {inv, shift}
#define WS_TOTAL 12384    // 49536 B

// crops tile: 36 rows x 36 cols x 8 ch (ch3..7 = 0), bf16, row pitch 304 u16
#define CI_PITCH 304
#define CI_U32   (36 * 152)               // 5472 u32 = 21888 B
// LDS: 21888 (uniS) + 18496 (hS) + 512 (bn2) + 32 (red) = 40928 B -> 4 blocks/CU

// ================= prep: build all block-invariant tables once ==============
__global__ __launch_bounds__(512) void prep_kernel(
    const float* __restrict__ w1, const float* __restrict__ b1,
    const float* __restrict__ g1, const float* __restrict__ be1,
    const float* __restrict__ m1, const float* __restrict__ v1,
    const float* __restrict__ w2, const float* __restrict__ b2,
    const float* __restrict__ g2, const float* __restrict__ be2,
    const float* __restrict__ m2, const float* __restrict__ v2,
    u32_t* __restrict__ ws)
{
    const int tid = threadIdx.x;
    ws[WSUM_OFF + tid] = 0u;                       // zero wsum[512]

    // w2r: [H][tap][ocl][icp] = packbf(w2[oc][2icp][tap], w2[oc][2icp+1][tap])
    for (int idx = tid; idx < 9216; idx += 512) {
        int H   = idx / 4608;
        int rem = idx - H * 4608;
        int tap = rem >> 9;
        int r2  = rem & 511;
        int ocl = r2 >> 4;
        int icp = r2 & 15;
        const float* wp = w2 + (H * 32 + ocl) * 288 + tap;
        ws[W2R_OFF + idx] = packbf(wp[(2 * icp) * 9], wp[(2 * icp + 1) * 9]);
    }
    // wf: conv1 B-frag for (s, lane): k=halfk*8+j covers pixel 2s+halfk, ic=j<3
    if (tid < 320) {
        int s = tid >> 6, lane = tid & 63;
        int n32 = lane & 31, halfk = lane >> 5;
        int p = 2 * s + halfk;
        bool valid = (p <= 8);
        const float* wp = w1 + n32 * 27 + (valid ? p : 8);
        float wa = valid ? wp[0]  : 0.f;
        float wb = valid ? wp[9]  : 0.f;
        float wc = valid ? wp[18] : 0.f;
        u32x4 f;
        f[0] = packbf(wa, wb); f[1] = packbf(wc, 0.f); f[2] = 0u; f[3] = 0u;
        ((u32x4_ma*)(ws + WF_OFF))[tid] = f;
    }
    // ptab: conv1 A-side base offset (u16 units) for (tt, n32)
    for (int idx = tid; idx < 1184; idx += 512) {
        int tt = idx >> 5, n32 = idx & 31;
        int gA = n32 >> 2, sub = n32 & 3;
        int pA = tt * 8 + gA;
        int gy = (pA * 241) >> 12; gy = min(gy, 16);
        int gx = min(pA - gy * 17, 16);
        int cy = 2 * gy + (sub >> 1), cx = 2 * gx + (sub & 1);
        ws[PT_OFF + idx] = (u32_t)(cy * CI_PITCH + cx * 8);
    }
    if (tid < 32) {
        float inv = g1[tid] * rsqrtf(v1[tid] + BN_EPS);
        float sh  = b1[tid] * inv + be1[tid] - m1[tid] * inv;
        ws[BN1_OFF + 2 * tid]     = __float_as_uint(inv);
        ws[BN1_OFF + 2 * tid + 1] = __float_as_uint(sh);
    }
    if (tid >= 64 && tid < 128) {
        int ch = tid - 64;
        float inv = g2[ch] * rsqrtf(v2[ch] + BN_EPS);
        float sh  = b2[ch] * inv + be2[ch] - m2[ch] * inv;
        ws[BN2_OFF + 2 * ch]     = __float_as_uint(inv);
        ws[BN2_OFF + 2 * ch + 1] = __float_as_uint(sh);
    }
}

// ============================ fused CNN =====================================
__global__ __launch_bounds__(512, 8) void fused_cnn_kernel(
    const float* __restrict__ crops, const u32_t* __restrict__ tab,
    float* __restrict__ out, float* __restrict__ wsum)
{
    __shared__ __align__(16) u32_t uniS[CI_U32];   // crops-interleaved ∪ w2r-half
    __shared__ __align__(16) u16_t hS[289 * 32];   // pooled h, [pgrp][32 ic] bf16
    __shared__ float bn2S[128];
    __shared__ float redS[8];

    const int tid  = threadIdx.x;
    const int wave = tid >> 6;
    const int lane = tid & 63;
    const int quad = lane >> 4;
    const int r    = lane & 15;
    const int n32  = lane & 31;
    const int halfk = lane >> 5;

    const int blk = blockIdx.x;
    const int img = blk >> 4;
    const int t   = blk & 15;
    const int fy0 = (t >> 2) * 4;
    const int fx0 = (t & 3) * 4;
    const int crop_y0 = 8 * fy0 - 3;
    const int crop_x0 = 8 * fx0 - 3;
    const bool interior = (fy0 != 0) && (fx0 != 0);

    // ---- Phase 0: stage crops (full 8-ch b128 writes); bn2 table copy ----
    if (tid < 128) bn2S[tid] = __uint_as_float(tab[BN2_OFF + tid]);
    const float* cbase = crops + (size_t)img * (3 * HW_ * HW_);
    #pragma unroll
    for (int i = 0; i < 3; ++i) {
        int idx = tid + 512 * i;
        if (idx < 1296) {
            int rr = (idx * 1821) >> 16;          // idx/36, exact for idx<1296
            int cc = idx - rr * 36;
            int gr = crop_y0 + rr, gc = crop_x0 + cc;
            float v0 = 0.f, v1v = 0.f, v2v = 0.f;
            if (gr >= 0 && gr < HW_ && gc >= 0 && gc < HW_) {
                const float* p = cbase + gr * HW_ + gc;
                v0  = p[0];
                v1v = p[HW_ * HW_];
                v2v = p[2 * HW_ * HW_];
            }
            u32x4 w;
            w[0] = packbf(v0, v1v); w[1] = packbf(v2v, 0.f); w[2] = 0u; w[3] = 0u;
            *(u32x4_ma*)&uniS[rr * 152 + cc * 4] = w;
        }
    }

    // ---- conv1 B-frags + bn1 from tables ----
    u32x4 wf[5];
    const u32x4_ma* wft = (const u32x4_ma*)(tab + WF_OFF);
    #pragma unroll
    for (int s = 0; s < 5; ++s) wf[s] = wft[s * 64 + lane];
    const float inv1 = __uint_as_float(tab[BN1_OFF + 2 * n32]);
    const float sh1  = __uint_as_float(tab[BN1_OFF + 2 * n32 + 1]);
    __syncthreads();

    // ---- Phase 1: conv1 via 32x32x16 MFMA, pool in-register -> hS ----
    const int off0 = halfk ? 8          : 0;
    const int off1 = halfk ? 304        : 16;
    const int off2 = halfk ? 304 + 16   : 304 + 8;
    const int off3 = halfk ? 608 + 8    : 608;
    const int off4 = 608 + 16;
    const u16_t* cropsI = (const u16_t*)uniS;

    #pragma unroll 1
    for (int tt = wave; tt < 37; tt += 8) {
        const u16_t* base = cropsI + tab[PT_OFF + tt * 32 + n32];

        bf16x8 a0 = ld_frag16(base + off0);
        bf16x8 a1 = ld_frag16(base + off1);
        bf16x8 a2 = ld_frag16(base + off2);
        bf16x8 a3 = ld_frag16(base + off3);
        bf16x8 a4 = ld_frag16(base + off4);

        f32x16 acc = {0.f,0.f,0.f,0.f,0.f,0.f,0.f,0.f,
                      0.f,0.f,0.f,0.f,0.f,0.f,0.f,0.f};
        acc = __builtin_amdgcn_mfma_f32_32x32x16_bf16(a0, asbf(wf[0]), acc, 0, 0, 0);
        acc = __builtin_amdgcn_mfma_f32_32x32x16_bf16(a1, asbf(wf[1]), acc, 0, 0, 0);
        acc = __builtin_amdgcn_mfma_f32_32x32x16_bf16(a2, asbf(wf[2]), acc, 0, 0, 0);
        acc = __builtin_amdgcn_mfma_f32_32x32x16_bf16(a3, asbf(wf[3]), acc, 0, 0, 0);
        acc = __builtin_amdgcn_mfma_f32_32x32x16_bf16(a4, asbf(wf[4]), acc, 0, 0, 0);

        // D rows for reg-quad q: pool group pD = tt*8 + 2q + halfk
        #pragma unroll
        for (int q = 0; q < 4; ++q) {
            int pD = tt * 8 + 2 * q + halfk;
            float m4 = fmaxf(fmaxf(acc[4 * q], acc[4 * q + 1]),
                             fmaxf(acc[4 * q + 2], acc[4 * q + 3]));
            float val = fmaxf(fmaf(m4, inv1, sh1), 0.f);
            if (!interior) {          // edge tiles: zero outside global 64x64
                int gyD = (pD * 241) >> 12;
                int gxD = pD - gyD * 17;
                int y2 = 4 * fy0 - 1 + gyD, x2 = 4 * fx0 - 1 + gxD;
                if (y2 < 0 || y2 > 63 || x2 < 0 || x2 > 63) val = 0.f;
            }
            if (pD < 289) hS[pD * 32 + n32] = f2bf(val);
        }
    }
    __syncthreads();   // hS complete; cropsI region now dead

    // ---- Phase 2: conv2 (16x16x32) in two oc-halves; score partial sum ----
    float* outp = out + (size_t)img * 16384;
    const f32x4 zero4 = {0.f, 0.f, 0.f, 0.f};
    float ssum = 0.f;
    #pragma unroll 1
    for (int H = 0; H < 2; ++H) {
        // stage prebuilt w2r half via pure b128 copies
        const u32x4_ma* w2t = (const u32x4_ma*)(tab + W2R_OFF + H * 4608);
        u32x4_ma* uni4 = (u32x4_ma*)uniS;
        for (int i = tid; i < 1152; i += 512) uni4[i] = w2t[i];
        __syncthreads();

        const int mt  = wave & 1;                     // oc-tile within half
        const int nt0 = wave >> 1;                    // conv-pos row-pair 0..3
        const int rhi = r >> 3, rlo = r & 7;
        f32x4 acc = zero4;
        #pragma unroll
        for (int s = 0; s < 9; ++s) {
            const int ky = s / 3, kx = s - 3 * (s / 3);
            bf16x8 af = ld_frag32(&uniS[(s * 32 + mt * 16 + r) * 16 + quad * 4]);
            int hrow = 4 * nt0 + 2 * rhi + ky;
            int hcol = 2 * rlo + kx;
            bf16x8 bx = ld_frag16(&hS[(hrow * 17 + hcol) * 32 + quad * 8]);
            acc = __builtin_amdgcn_mfma_f32_16x16x32_bf16(af, bx, acc, 0, 0, 0);
        }
        // epilogue: maxpool via shfl (partners r^1, r^8), BN + sigmoid
        const bool active = ((r & 9) == 0);           // r in {0,2,4,6}
        const int fxl = r >> 1;
        const int fy  = fy0 + nt0;
        #pragma unroll
        for (int reg = 0; reg < 4; ++reg) {
            int oc = H * 32 + mt * 16 + quad * 4 + reg;
            float v = acc[reg];
            float m = fmaxf(v, __shfl_xor(v, 1));
            m = fmaxf(m, __shfl_xor(m, 8));
            float z = fmaf(m, bn2S[oc * 2], bn2S[oc * 2 + 1]);
            float sig = 1.f / (1.f + expf(-z));
            if (active) {
                outp[oc * 256 + fy * 16 + fx0 + fxl] = sig;
                ssum += sig;
            }
        }
        if (H == 0) __syncthreads();   // before re-staging w2r half 1
    }

    // ---- block score partial -> global atomic ----
    #pragma unroll
    for (int off = 32; off > 0; off >>= 1)
        ssum += __shfl_xor(ssum, off);
    if (lane == 0) redS[wave] = ssum;
    __syncthreads();
    if (tid == 0) {
        float bs = 0.f;
        #pragma unroll
        for (int w = 0; w < 8; ++w) bs += redS[w];
        atomicAdd(&wsum[img], bs);
    }
}

__global__ void finalize_kernel(const float* __restrict__ ws,
                                float* __restrict__ scores,
                                float* __restrict__ detected) {
    int i = threadIdx.x;
    float mean = ws[i] * (1.f / 16384.f);
    scores[i] = mean;
    detected[i] = (mean >= 0.55f) ? 1.f : 0.f;
}

extern "C" void kernel_launch(void* const* d_in, const int* in_sizes, int n_in,
                              void* d_out, int out_size, void* d_ws, size_t ws_size,
                              hipStream_t stream) {
    (void)in_sizes; (void)n_in; (void)out_size; (void)ws_size;
    const float* crops = (const float*)d_in[0];
    const float* w1  = (const float*)d_in[1];
    const float* b1  = (const float*)d_in[2];
    const float* g1  = (const float*)d_in[3];
    const float* be1 = (const float*)d_in[4];
    const float* m1  = (const float*)d_in[5];
    const float* v1  = (const float*)d_in[6];
    const float* w2  = (const float*)d_in[7];
    const float* b2  = (const float*)d_in[8];
    const float* g2  = (const float*)d_in[9];
    const float* be2 = (const float*)d_in[10];
    const float* m2  = (const float*)d_in[11];
    const float* v2  = (const float*)d_in[12];
    float* out = (float*)d_out;
    u32_t* ws  = (u32_t*)d_ws;

    prep_kernel<<<1, 512, 0, stream>>>(
        w1, b1, g1, be1, m1, v1, w2, b2, g2, be2, m2, v2, ws);
    fused_cnn_kernel<<<8192, 512, 0, stream>>>(
        crops, ws, out, (float*)ws);
    finalize_kernel<<<1, 512, 0, stream>>>(
        (const float*)ws, out + 8388608, out + 8388608 + 512);
}

// Round 8
// 289.730 us; speedup vs baseline: 3.5477x; 1.0688x over previous
//
#include <hip/hip_runtime.h>
#include <math.h>

#define BN_EPS 1e-5f
#define HW_ 128

typedef unsigned short u16_t;
typedef unsigned int u32_t;

typedef __bf16 bf16x8 __attribute__((ext_vector_type(8)));
typedef float f32x4 __attribute__((ext_vector_type(4)));
typedef float f32x16 __attribute__((ext_vector_type(16)));
typedef u32_t u32x4 __attribute__((ext_vector_type(4)));
typedef u32x4 u32x4_ma __attribute__((may_alias));
typedef u16_t u16_ma __attribute__((may_alias));

static __device__ __forceinline__ u16_t f2bf(float f) {
    u32_t u = __float_as_uint(f);
    return (u16_t)((u + 0x7FFFu + ((u >> 16) & 1u)) >> 16);
}
static __device__ __forceinline__ u32_t packbf(float a, float b) {
    return (u32_t)f2bf(a) | ((u32_t)f2bf(b) << 16);
}
static __device__ __forceinline__ bf16x8 ld_frag16(const u16_t* p) {
    union { u32x4 u; bf16x8 f; } x;
    x.u = *(const u32x4_ma*)p;
    return x.f;
}
static __device__ __forceinline__ bf16x8 ld_frag32(const u32_t* p) {
    union { u32x4 u; bf16x8 f; } x;
    x.u = *(const u32x4_ma*)p;
    return x.f;
}
static __device__ __forceinline__ bf16x8 asbf(u32x4 u) {
    union { u32x4 u; bf16x8 f; } x;
    x.u = u;
    return x.f;
}

// ---- d_ws table layout (u32 units) ----
#define WSUM_OFF 0        // 512 floats (per-image sigmoid sums)
#define W2R_OFF  512      // 9216 u32: [H][tap][32 ocl][16 icp] packed bf16 pairs
#define WF_OFF   9728     // 5*64 uint4 = 1280 u32: conv1 B-frags [s][lane]
#define PT_OFF   11008    // 1280 u32: conv1 A base offsets [tt(40)][n32]
#define BN1_OFF  12288    // 64 u32: 32 x {inv, shift}
#define BN2_OFF  12352    // 128 u32: 64 x {inv, shift}
#define WS_TOTAL 12480    // 49920 B

// crops tile: 36 rows x 36 cols x 8 ch (ch3..7 = 0), bf16, row pitch 304 u16
#define CI_PITCH 304
#define CI_U32   (36 * 152)               // 5472 u32 = 21888 B
// LDS: 21888 (uniS) + 18496 (hS) + 32 (red) = 40416 B -> 4 blocks/CU

// ================= prep: build all block-invariant tables once ==============
__global__ __launch_bounds__(512) void prep_kernel(
    const float* __restrict__ w1, const float* __restrict__ b1,
    const float* __restrict__ g1, const float* __restrict__ be1,
    const float* __restrict__ m1, const float* __restrict__ v1,
    const float* __restrict__ w2, const float* __restrict__ b2,
    const float* __restrict__ g2, const float* __restrict__ be2,
    const float* __restrict__ m2, const float* __restrict__ v2,
    u32_t* __restrict__ ws)
{
    const int tid = threadIdx.x;
    ws[WSUM_OFF + tid] = 0u;                       // zero wsum[512]

    // w2r: [H][tap][ocl][icp] = packbf(w2[oc][2icp][tap], w2[oc][2icp+1][tap])
    for (int idx = tid; idx < 9216; idx += 512) {
        int H   = idx / 4608;
        int rem = idx - H * 4608;
        int tap = rem >> 9;
        int r2  = rem & 511;
        int ocl = r2 >> 4;
        int icp = r2 & 15;
        const float* wp = w2 + (H * 32 + ocl) * 288 + tap;
        ws[W2R_OFF + idx] = packbf(wp[(2 * icp) * 9], wp[(2 * icp + 1) * 9]);
    }
    // wf: conv1 B-frag for (s, lane): k=halfk*8+j covers pixel 2s+halfk, ic=j<3
    if (tid < 320) {
        int s = tid >> 6, lane = tid & 63;
        int n32 = lane & 31, halfk = lane >> 5;
        int p = 2 * s + halfk;
        bool valid = (p <= 8);
        const float* wp = w1 + n32 * 27 + (valid ? p : 8);
        float wa = valid ? wp[0]  : 0.f;
        float wb = valid ? wp[9]  : 0.f;
        float wc = valid ? wp[18] : 0.f;
        u32x4 f;
        f[0] = packbf(wa, wb); f[1] = packbf(wc, 0.f); f[2] = 0u; f[3] = 0u;
        ((u32x4_ma*)(ws + WF_OFF))[tid] = f;
    }
    // ptab: conv1 A-side base offset (u16 units) for (tt<40, n32); clamped
    for (int idx = tid; idx < 1280; idx += 512) {
        int tt = idx >> 5, n32 = idx & 31;
        int gA = n32 >> 2, sub = n32 & 3;
        int pA = tt * 8 + gA;
        int gy = (pA * 241) >> 12; gy = min(gy, 16);
        int gx = min(pA - gy * 17, 16); gx = max(gx, 0);
        int cy = 2 * gy + (sub >> 1), cx = 2 * gx + (sub & 1);
        ws[PT_OFF + idx] = (u32_t)(cy * CI_PITCH + cx * 8);
    }
    if (tid < 32) {
        float inv = g1[tid] * rsqrtf(v1[tid] + BN_EPS);
        float sh  = b1[tid] * inv + be1[tid] - m1[tid] * inv;
        ws[BN1_OFF + 2 * tid]     = __float_as_uint(inv);
        ws[BN1_OFF + 2 * tid + 1] = __float_as_uint(sh);
    }
    if (tid >= 64 && tid < 128) {
        int ch = tid - 64;
        float inv = g2[ch] * rsqrtf(v2[ch] + BN_EPS);
        float sh  = b2[ch] * inv + be2[ch] - m2[ch] * inv;
        ws[BN2_OFF + 2 * ch]     = __float_as_uint(inv);
        ws[BN2_OFF + 2 * ch + 1] = __float_as_uint(sh);
    }
}

// ============================ fused CNN =====================================
// hS swizzle: logical (group p, ch-chunk c of 4) stored at physical chunk
// c ^ ((p>>1)&3) -> phase-2 lane-stride (2 groups = 128 B = bank period)
// spreads across all 4 chunks => <=2-way (free) instead of 8-way.
__global__ __launch_bounds__(512, 8) void fused_cnn_kernel(
    const float* __restrict__ crops, const u32_t* __restrict__ tab,
    float* __restrict__ out, float* __restrict__ wsum)
{
    __shared__ __align__(16) u32_t uniS[CI_U32];   // crops-interleaved tile
    __shared__ __align__(16) u16_t hS[289 * 32];   // pooled h (swizzled chunks)
    __shared__ float redS[8];

    const int tid  = threadIdx.x;
    const int wave = tid >> 6;
    const int lane = tid & 63;
    const int quad = lane >> 4;
    const int r    = lane & 15;
    const int n32  = lane & 31;
    const int halfk = lane >> 5;

    const int blk = blockIdx.x;
    const int img = blk >> 4;
    const int t   = blk & 15;
    const int fy0 = (t >> 2) * 4;
    const int fx0 = (t & 3) * 4;
    const int crop_y0 = 8 * fy0 - 3;
    const int crop_x0 = 8 * fx0 - 3;
    const bool interior = (fy0 != 0) && (fx0 != 0);

    // ---- Phase 0: stage crops (full 8-ch b128 writes) ----
    const float* cbase = crops + (size_t)img * (3 * HW_ * HW_);
    #pragma unroll
    for (int i = 0; i < 3; ++i) {
        int idx = tid + 512 * i;
        if (idx < 1296) {
            int rr = (idx * 1821) >> 16;          // idx/36, exact for idx<1296
            int cc = idx - rr * 36;
            int gr = crop_y0 + rr, gc = crop_x0 + cc;
            float v0 = 0.f, v1v = 0.f, v2v = 0.f;
            if (gr >= 0 && gr < HW_ && gc >= 0 && gc < HW_) {
                const float* p = cbase + gr * HW_ + gc;
                v0  = p[0];
                v1v = p[HW_ * HW_];
                v2v = p[2 * HW_ * HW_];
            }
            u32x4 w;
            w[0] = packbf(v0, v1v); w[1] = packbf(v2v, 0.f); w[2] = 0u; w[3] = 0u;
            *(u32x4_ma*)&uniS[rr * 152 + cc * 4] = w;
        }
    }

    // ---- conv1 B-frags + bn1 from tables ----
    u32x4 wf[5];
    const u32x4_ma* wft = (const u32x4_ma*)(tab + WF_OFF);
    #pragma unroll
    for (int s = 0; s < 5; ++s) wf[s] = wft[s * 64 + lane];
    const float inv1 = __uint_as_float(tab[BN1_OFF + 2 * n32]);
    const float sh1  = __uint_as_float(tab[BN1_OFF + 2 * n32 + 1]);
    __syncthreads();

    // ---- Phase 1: conv1 via 32x32x16 MFMA, pool in-register -> hS ----
    const int off0 = halfk ? 8          : 0;
    const int off1 = halfk ? 304        : 16;
    const int off2 = halfk ? 304 + 16   : 304 + 8;
    const int off3 = halfk ? 608 + 8    : 608;
    const int off4 = 608 + 16;
    const u16_t* cropsI = (const u16_t*)uniS;
    const int hsub = n32 & 7;                      // within-chunk ch offset
    const int hchk = n32 >> 3;                     // logical ch-chunk

    #pragma unroll
    for (int i = 0; i < 5; ++i) {                  // uniform 5 trips (tt<40)
        int tt = wave + 8 * i;
        const u16_t* base = cropsI + tab[PT_OFF + tt * 32 + n32];

        bf16x8 a0 = ld_frag16(base + off0);
        bf16x8 a1 = ld_frag16(base + off1);
        bf16x8 a2 = ld_frag16(base + off2);
        bf16x8 a3 = ld_frag16(base + off3);
        bf16x8 a4 = ld_frag16(base + off4);

        f32x16 acc = {0.f,0.f,0.f,0.f,0.f,0.f,0.f,0.f,
                      0.f,0.f,0.f,0.f,0.f,0.f,0.f,0.f};
        acc = __builtin_amdgcn_mfma_f32_32x32x16_bf16(a0, asbf(wf[0]), acc, 0, 0, 0);
        acc = __builtin_amdgcn_mfma_f32_32x32x16_bf16(a1, asbf(wf[1]), acc, 0, 0, 0);
        acc = __builtin_amdgcn_mfma_f32_32x32x16_bf16(a2, asbf(wf[2]), acc, 0, 0, 0);
        acc = __builtin_amdgcn_mfma_f32_32x32x16_bf16(a3, asbf(wf[3]), acc, 0, 0, 0);
        acc = __builtin_amdgcn_mfma_f32_32x32x16_bf16(a4, asbf(wf[4]), acc, 0, 0, 0);

        // D rows for reg-quad q: pool group pD = tt*8 + 2q + halfk
        #pragma unroll
        for (int q = 0; q < 4; ++q) {
            int pD = tt * 8 + 2 * q + halfk;
            float m4 = fmaxf(fmaxf(acc[4 * q], acc[4 * q + 1]),
                             fmaxf(acc[4 * q + 2], acc[4 * q + 3]));
            float val = fmaxf(fmaf(m4, inv1, sh1), 0.f);
            if (!interior) {          // edge tiles: zero outside global 64x64
                int gyD = (pD * 241) >> 12;
                int gxD = pD - gyD * 17;
                int y2 = 4 * fy0 - 1 + gyD, x2 = 4 * fx0 - 1 + gxD;
                if (y2 < 0 || y2 > 63 || x2 < 0 || x2 > 63) val = 0.f;
            }
            if (pD < 289) {
                int chk = hchk ^ ((pD >> 1) & 3);
                hS[pD * 32 + chk * 8 + hsub] = f2bf(val);
            }
        }
    }
    __syncthreads();   // hS complete

    // ---- Phase 2: conv2 (A = h positions, B = weights from global) ----
    // Lane reads A-frag for position m=r: group g=r>>2, sub=r&3.
    // D: col = r = oc-local (constant/lane), row = quad*4+reg = 4 subs of
    // pool group 'quad' -> in-register maxpool, 1 store/lane/half.
    float* outp = out + (size_t)img * 16384;
    const f32x4 zero4 = {0.f, 0.f, 0.f, 0.f};
    const int mt  = wave & 1;                      // oc-tile within half
    const int nt0 = wave >> 1;                     // feat row 0..3
    const int cy2 = 2 * nt0 + ((r >> 1) & 1);      // A-side conv-out row
    const int cx2 = 2 * (r >> 2) + (r & 1);        // A-side conv-out col
    const int fy  = fy0 + nt0;
    float ssum = 0.f;
    #pragma unroll 1
    for (int H = 0; H < 2; ++H) {
        const u32_t* wz = tab + W2R_OFF + H * 4608;
        const int oc = H * 32 + mt * 16 + r;
        const float s2  = __uint_as_float(tab[BN2_OFF + 2 * oc]);
        const float sh2 = __uint_as_float(tab[BN2_OFF + 2 * oc + 1]);
        f32x4 acc = zero4;
        #pragma unroll
        for (int s = 0; s < 9; ++s) {
            const int ky = s / 3, kx = s - 3 * (s / 3);
            int p = (2 * cy2 + ky) * 17 + (2 * cx2 + kx);
            bf16x8 ah = ld_frag16(&hS[p * 32 + ((quad ^ ((p >> 1) & 3)) << 3)]);
            bf16x8 bw = ld_frag32(&wz[(s * 32 + mt * 16 + r) * 16 + quad * 4]);
            acc = __builtin_amdgcn_mfma_f32_16x16x32_bf16(ah, bw, acc, 0, 0, 0);
        }
        float m4 = fmaxf(fmaxf(acc[0], acc[1]), fmaxf(acc[2], acc[3]));
        float z = fmaf(m4, s2, sh2);
        float sig = 1.f / (1.f + expf(-z));
        outp[oc * 256 + fy * 16 + fx0 + quad] = sig;
        ssum += sig;
    }

    // ---- block score partial -> global atomic ----
    #pragma unroll
    for (int off = 32; off > 0; off >>= 1)
        ssum += __shfl_xor(ssum, off);
    if (lane == 0) redS[wave] = ssum;
    __syncthreads();
    if (tid == 0) {
        float bs = 0.f;
        #pragma unroll
        for (int w = 0; w < 8; ++w) bs += redS[w];
        atomicAdd(&wsum[img], bs);
    }
}

__global__ void finalize_kernel(const float* __restrict__ ws,
                                float* __restrict__ scores,
                                float* __restrict__ detected) {
    int i = threadIdx.x;
    float mean = ws[i] * (1.f / 16384.f);
    scores[i] = mean;
    detected[i] = (mean >= 0.55f) ? 1.f : 0.f;
}

extern "C" void kernel_launch(void* const* d_in, const int* in_sizes, int n_in,
                              void* d_out, int out_size, void* d_ws, size_t ws_size,
                              hipStream_t stream) {
    (void)in_sizes; (void)n_in; (void)out_size; (void)ws_size;
    const float* crops = (const float*)d_in[0];
    const float* w1  = (const float*)d_in[1];
    const float* b1  = (const float*)d_in[2];
    const float* g1  = (const float*)d_in[3];
    const float* be1 = (const float*)d_in[4];
    const float* m1  = (const float*)d_in[5];
    const float* v1  = (const float*)d_in[6];
    const float* w2  = (const float*)d_in[7];
    const float* b2  = (const float*)d_in[8];
    const float* g2  = (const float*)d_in[9];
    const float* be2 = (const float*)d_in[10];
    const float* m2  = (const float*)d_in[11];
    const float* v2  = (const float*)d_in[12];
    float* out = (float*)d_out;
    u32_t* ws  = (u32_t*)d_ws;

    prep_kernel<<<1, 512, 0, stream>>>(
        w1, b1, g1, be1, m1, v1, w2, b2, g2, be2, m2, v2, ws);
    fused_cnn_kernel<<<8192, 512, 0, stream>>>(
        crops, ws, out, (float*)ws);
    finalize_kernel<<<1, 512, 0, stream>>>(
        (const float*)ws, out + 8388608, out + 8388608 + 512);
}

// Round 9
// 286.583 us; speedup vs baseline: 3.5866x; 1.0110x over previous
//
#include <hip/hip_runtime.h>
#include <math.h>

#define BN_EPS 1e-5f
#define HW_ 128

typedef unsigned short u16_t;
typedef unsigned int u32_t;

typedef __bf16 bf16x8 __attribute__((ext_vector_type(8)));
typedef float f32x4 __attribute__((ext_vector_type(4)));
typedef float f32x16 __attribute__((ext_vector_type(16)));
typedef u32_t u32x4 __attribute__((ext_vector_type(4)));
typedef u32_t u32x2 __attribute__((ext_vector_type(2)));
typedef u32x4 u32x4_ma __attribute__((may_alias));
typedef u32x2 u32x2_ma __attribute__((may_alias));

static __device__ __forceinline__ u16_t f2bf(float f) {
    u32_t u = __float_as_uint(f);
    return (u16_t)((u + 0x7FFFu + ((u >> 16) & 1u)) >> 16);
}
static __device__ __forceinline__ u32_t packbf(float a, float b) {
    return (u32_t)f2bf(a) | ((u32_t)f2bf(b) << 16);
}
static __device__ __forceinline__ bf16x8 ld_frag16(const u16_t* p) {
    union { u32x4 u; bf16x8 f; } x;
    x.u = *(const u32x4_ma*)p;
    return x.f;
}
static __device__ __forceinline__ bf16x8 ld_frag32(const u32_t* p) {
    union { u32x4 u; bf16x8 f; } x;
    x.u = *(const u32x4_ma*)p;
    return x.f;
}
static __device__ __forceinline__ bf16x8 asbf(u32x4 u) {
    union { u32x4 u; bf16x8 f; } x;
    x.u = u;
    return x.f;
}

// ---- d_ws table layout (u32 units) ----
#define WSUM_OFF 0        // 512 floats (per-image sigmoid sums)
#define W2R_OFF  512      // 9216 u32: [H][tap][32 ocl][16 icp] packed bf16 pairs
#define WF_OFF   9728     // 3*64 uint4 = 768 u32: conv1 B-frags [s][lane]
#define PT_OFF   10496    // 2560 u32: conv1 A base offsets (u32 units) [tt(40)][lane]
#define BN1_OFF  13056    // 64 u32: 32 x {inv, shift}
#define BN2_OFF  13120    // 128 u32: 64 x {inv, shift}
#define WS_TOTAL 13248    // 52992 B

// crops tile: 36 rows x 37 cols x 4 ch (ch3 = 0), bf16. Pixel = 8 B (2 u32).
// Row pitch = 37*2 = 74 u32. Col 36 is an in-bounds pad (only ever hits kx=3,
// whose weight is 0 -> value irrelevant but must be finite).
#define CI_U32   (36 * 74)                // 2664 u32 = 10656 B
// LDS: 10656 (uniS) + 18496 (hS) + 32 (red) = 29184 B -> wave-capped 4 blocks/CU

// ================= prep: build all block-invariant tables once ==============
__global__ __launch_bounds__(512) void prep_kernel(
    const float* __restrict__ w1, const float* __restrict__ b1,
    const float* __restrict__ g1, const float* __restrict__ be1,
    const float* __restrict__ m1, const float* __restrict__ v1,
    const float* __restrict__ w2, const float* __restrict__ b2,
    const float* __restrict__ g2, const float* __restrict__ be2,
    const float* __restrict__ m2, const float* __restrict__ v2,
    u32_t* __restrict__ ws)
{
    const int tid = threadIdx.x;
    ws[WSUM_OFF + tid] = 0u;                       // zero wsum[512]

    // w2r: [H][tap][ocl][icp] = packbf(w2[oc][2icp][tap], w2[oc][2icp+1][tap])
    for (int idx = tid; idx < 9216; idx += 512) {
        int H   = idx / 4608;
        int rem = idx - H * 4608;
        int tap = rem >> 9;
        int r2  = rem & 511;
        int ocl = r2 >> 4;
        int icp = r2 & 15;
        const float* wp = w2 + (H * 32 + ocl) * 288 + tap;
        ws[W2R_OFF + idx] = packbf(wp[(2 * icp) * 9], wp[(2 * icp + 1) * 9]);
    }
    // wf: conv1 B-frag for (s=ky, lane): k = halfk*8+j; pixel kx = 2*halfk+(j>>2),
    // ch = j&3; value = w1[oc=n32][ch][ky][kx] for kx<3 && ch<3, else 0.
    if (tid < 192) {
        int s = tid >> 6, lane = tid & 63;
        int n32 = lane & 31, h = lane >> 5;
        u32x4 f;
        #pragma unroll
        for (int jp = 0; jp < 4; ++jp) {
            int j0 = 2 * jp, j1 = 2 * jp + 1;
            int kx0 = 2 * h + (j0 >> 2), ch0 = j0 & 3;
            int kx1 = 2 * h + (j1 >> 2), ch1 = j1 & 3;
            float va = (kx0 < 3 && ch0 < 3) ? w1[n32 * 27 + ch0 * 9 + s * 3 + kx0] : 0.f;
            float vb = (kx1 < 3 && ch1 < 3) ? w1[n32 * 27 + ch1 * 9 + s * 3 + kx1] : 0.f;
            f[jp] = packbf(va, vb);
        }
        ((u32x4_ma*)(ws + WF_OFF))[tid] = f;
    }
    // ptab: conv1 A base offset in u32 units for (tt<40, lane); pA clamped.
    for (int idx = tid; idx < 2560; idx += 512) {
        int tt = idx >> 6, lane = idx & 63;
        int n32 = lane & 31, h = lane >> 5;
        int gA = n32 >> 2, sub = n32 & 3;
        int pA = tt * 8 + gA;
        int gy = (pA * 241) >> 12; gy = min(gy, 16);
        int gx = min(pA - gy * 17, 16); gx = max(gx, 0);
        int cy = 2 * gy + (sub >> 1), cx = 2 * gx + (sub & 1);
        ws[PT_OFF + idx] = (u32_t)((cy * 37 + cx + 2 * h) * 2);
    }
    if (tid < 32) {
        float inv = g1[tid] * rsqrtf(v1[tid] + BN_EPS);
        float sh  = b1[tid] * inv + be1[tid] - m1[tid] * inv;
        ws[BN1_OFF + 2 * tid]     = __float_as_uint(inv);
        ws[BN1_OFF + 2 * tid + 1] = __float_as_uint(sh);
    }
    if (tid >= 64 && tid < 128) {
        int ch = tid - 64;
        float inv = g2[ch] * rsqrtf(v2[ch] + BN_EPS);
        float sh  = b2[ch] * inv + be2[ch] - m2[ch] * inv;
        ws[BN2_OFF + 2 * ch]     = __float_as_uint(inv);
        ws[BN2_OFF + 2 * ch + 1] = __float_as_uint(sh);
    }
}

// ============================ fused CNN =====================================
// hS swizzle: logical (group p, ch-chunk c of 4) stored at physical chunk
// c ^ ((p>>1)&3) -> phase-2 lane-stride (2 groups = 128 B = bank period)
// spreads across all 4 chunks => <=2-way (free) instead of 8-way.
__global__ __launch_bounds__(512, 8) void fused_cnn_kernel(
    const float* __restrict__ crops, const u32_t* __restrict__ tab,
    float* __restrict__ out, float* __restrict__ wsum)
{
    __shared__ __align__(16) u32_t uniS[CI_U32];   // crops 4-ch interleaved tile
    __shared__ __align__(16) u16_t hS[289 * 32];   // pooled h (swizzled chunks)
    __shared__ float redS[8];

    const int tid  = threadIdx.x;
    const int wave = tid >> 6;
    const int lane = tid & 63;
    const int quad = lane >> 4;
    const int r    = lane & 15;
    const int n32  = lane & 31;
    const int halfk = lane >> 5;

    const int blk = blockIdx.x;
    const int img = blk >> 4;
    const int t   = blk & 15;
    const int fy0 = (t >> 2) * 4;
    const int fx0 = (t & 3) * 4;
    const int crop_y0 = 8 * fy0 - 3;
    const int crop_x0 = 8 * fx0 - 3;
    const bool interior = (fy0 != 0) && (fx0 != 0);

    // ---- Phase 0: stage crops tile (one b64 write per pixel, ch3 = 0) ----
    const float* cbase = crops + (size_t)img * (3 * HW_ * HW_);
    #pragma unroll
    for (int i = 0; i < 3; ++i) {
        int idx = tid + 512 * i;
        if (idx < 1332) {                          // 36 rows x 37 cols
            int rr = (idx * 1772) >> 16;           // idx/37, exact for idx<1332
            int cc = idx - rr * 37;
            int gr = crop_y0 + rr, gc = crop_x0 + cc;
            float v0 = 0.f, v1v = 0.f, v2v = 0.f;
            if ((unsigned)gr < 128u && (unsigned)gc < 128u) {
                const float* p = cbase + gr * HW_ + gc;
                v0  = p[0];
                v1v = p[HW_ * HW_];
                v2v = p[2 * HW_ * HW_];
            }
            u32x2 w;
            w[0] = packbf(v0, v1v); w[1] = packbf(v2v, 0.f);
            *(u32x2_ma*)&uniS[idx * 2] = w;
        }
    }

    // ---- conv1 B-frags + bn1 from tables ----
    u32x4 wf[3];
    const u32x4_ma* wft = (const u32x4_ma*)(tab + WF_OFF);
    #pragma unroll
    for (int s = 0; s < 3; ++s) wf[s] = wft[s * 64 + lane];
    const float inv1 = __uint_as_float(tab[BN1_OFF + 2 * n32]);
    const float sh1  = __uint_as_float(tab[BN1_OFF + 2 * n32 + 1]);
    __syncthreads();

    // ---- Phase 1: conv1 via 32x32x16 MFMA (3 K-steps), pool in-reg -> hS ----
    const int hsub = n32 & 7;                      // within-chunk ch offset
    const int hchk = n32 >> 3;                     // logical ch-chunk

    #pragma unroll
    for (int i = 0; i < 5; ++i) {                  // uniform 5 trips (tt<40)
        int tt = wave + 8 * i;
        const u32_t* bp = uniS + tab[PT_OFF + tt * 64 + lane];

        // step ky: 16 B at bp + ky*74 u32 (8B-aligned -> 2 b64 loads)
        u32x2 l0a = *(const u32x2_ma*)(bp);
        u32x2 l0b = *(const u32x2_ma*)(bp + 2);
        u32x2 l1a = *(const u32x2_ma*)(bp + 74);
        u32x2 l1b = *(const u32x2_ma*)(bp + 76);
        u32x2 l2a = *(const u32x2_ma*)(bp + 148);
        u32x2 l2b = *(const u32x2_ma*)(bp + 150);
        u32x4 a0; a0[0] = l0a[0]; a0[1] = l0a[1]; a0[2] = l0b[0]; a0[3] = l0b[1];
        u32x4 a1; a1[0] = l1a[0]; a1[1] = l1a[1]; a1[2] = l1b[0]; a1[3] = l1b[1];
        u32x4 a2; a2[0] = l2a[0]; a2[1] = l2a[1]; a2[2] = l2b[0]; a2[3] = l2b[1];

        f32x16 acc = {0.f,0.f,0.f,0.f,0.f,0.f,0.f,0.f,
                      0.f,0.f,0.f,0.f,0.f,0.f,0.f,0.f};
        acc = __builtin_amdgcn_mfma_f32_32x32x16_bf16(asbf(a0), asbf(wf[0]), acc, 0, 0, 0);
        acc = __builtin_amdgcn_mfma_f32_32x32x16_bf16(asbf(a1), asbf(wf[1]), acc, 0, 0, 0);
        acc = __builtin_amdgcn_mfma_f32_32x32x16_bf16(asbf(a2), asbf(wf[2]), acc, 0, 0, 0);

        // D rows for reg-quad q: pool group pD = tt*8 + 2q + halfk
        #pragma unroll
        for (int q = 0; q < 4; ++q) {
            int pD = tt * 8 + 2 * q + halfk;
            float m4 = fmaxf(fmaxf(acc[4 * q], acc[4 * q + 1]),
                             fmaxf(acc[4 * q + 2], acc[4 * q + 3]));
            float val = fmaxf(fmaf(m4, inv1, sh1), 0.f);
            if (!interior) {          // edge tiles: zero outside global 64x64
                int gyD = (pD * 241) >> 12;
                int gxD = pD - gyD * 17;
                int y2 = 4 * fy0 - 1 + gyD, x2 = 4 * fx0 - 1 + gxD;
                if (y2 < 0 || y2 > 63 || x2 < 0 || x2 > 63) val = 0.f;
            }
            if (pD < 289) {
                int chk = hchk ^ ((pD >> 1) & 3);
                hS[pD * 32 + chk * 8 + hsub] = f2bf(val);
            }
        }
    }
    __syncthreads();   // hS complete

    // ---- Phase 2: conv2 (A = h positions, B = weights from global) ----
    float* outp = out + (size_t)img * 16384;
    const f32x4 zero4 = {0.f, 0.f, 0.f, 0.f};
    const int mt  = wave & 1;                      // oc-tile within half
    const int nt0 = wave >> 1;                     // feat row 0..3
    const int cy2 = 2 * nt0 + ((r >> 1) & 1);      // A-side conv-out row
    const int cx2 = 2 * (r >> 2) + (r & 1);        // A-side conv-out col
    const int fy  = fy0 + nt0;
    float ssum = 0.f;
    #pragma unroll 1
    for (int H = 0; H < 2; ++H) {
        const u32_t* wz = tab + W2R_OFF + H * 4608;
        const int oc = H * 32 + mt * 16 + r;
        const float s2  = __uint_as_float(tab[BN2_OFF + 2 * oc]);
        const float sh2 = __uint_as_float(tab[BN2_OFF + 2 * oc + 1]);
        f32x4 acc = zero4;
        #pragma unroll
        for (int s = 0; s < 9; ++s) {
            const int ky = s / 3, kx = s - 3 * (s / 3);
            int p = (2 * cy2 + ky) * 17 + (2 * cx2 + kx);
            bf16x8 ah = ld_frag16(&hS[p * 32 + ((quad ^ ((p >> 1) & 3)) << 3)]);
            bf16x8 bw = ld_frag32(&wz[(s * 32 + mt * 16 + r) * 16 + quad * 4]);
            acc = __builtin_amdgcn_mfma_f32_16x16x32_bf16(ah, bw, acc, 0, 0, 0);
        }
        float m4 = fmaxf(fmaxf(acc[0], acc[1]), fmaxf(acc[2], acc[3]));
        float z = fmaf(m4, s2, sh2);
        float sig = 1.f / (1.f + expf(-z));
        outp[oc * 256 + fy * 16 + fx0 + quad] = sig;
        ssum += sig;
    }

    // ---- block score partial -> global atomic ----
    #pragma unroll
    for (int off = 32; off > 0; off >>= 1)
        ssum += __shfl_xor(ssum, off);
    if (lane == 0) redS[wave] = ssum;
    __syncthreads();
    if (tid == 0) {
        float bs = 0.f;
        #pragma unroll
        for (int w = 0; w < 8; ++w) bs += redS[w];
        atomicAdd(&wsum[img], bs);
    }
}

__global__ void finalize_kernel(const float* __restrict__ ws,
                                float* __restrict__ scores,
                                float* __restrict__ detected) {
    int i = threadIdx.x;
    float mean = ws[i] * (1.f / 16384.f);
    scores[i] = mean;
    detected[i] = (mean >= 0.55f) ? 1.f : 0.f;
}

extern "C" void kernel_launch(void* const* d_in, const int* in_sizes, int n_in,
                              void* d_out, int out_size, void* d_ws, size_t ws_size,
                              hipStream_t stream) {
    (void)in_sizes; (void)n_in; (void)out_size; (void)ws_size;
    const float* crops = (const float*)d_in[0];
    const float* w1  = (const float*)d_in[1];
    const float* b1  = (const float*)d_in[2];
    const float* g1  = (const float*)d_in[3];
    const float* be1 = (const float*)d_in[4];
    const float* m1  = (const float*)d_in[5];
    const float* v1  = (const float*)d_in[6];
    const float* w2  = (const float*)d_in[7];
    const float* b2  = (const float*)d_in[8];
    const float* g2  = (const float*)d_in[9];
    const float* be2 = (const float*)d_in[10];
    const float* m2  = (const float*)d_in[11];
    const float* v2  = (const float*)d_in[12];
    float* out = (float*)d_out;
    u32_t* ws  = (u32_t*)d_ws;

    prep_kernel<<<1, 512, 0, stream>>>(
        w1, b1, g1, be1, m1, v1, w2, b2, g2, be2, m2, v2, ws);
    fused_cnn_kernel<<<8192, 512, 0, stream>>>(
        crops, ws, out, (float*)ws);
    finalize_kernel<<<1, 512, 0, stream>>>(
        (const float*)ws, out + 8388608, out + 8388608 + 512);
}

// Round 10
// 272.682 us; speedup vs baseline: 3.7695x; 1.0510x over previous
//
#include <hip/hip_runtime.h>
#include <math.h>

#define BN_EPS 1e-5f
#define HW_ 128

typedef unsigned short u16_t;
typedef unsigned int u32_t;

typedef __bf16 bf16x8 __attribute__((ext_vector_type(8)));
typedef float f32x4 __attribute__((ext_vector_type(4)));
typedef float f32x16 __attribute__((ext_vector_type(16)));
typedef u32_t u32x4 __attribute__((ext_vector_type(4)));
typedef u32_t u32x2 __attribute__((ext_vector_type(2)));
typedef u32x4 u32x4_ma __attribute__((may_alias));
typedef u32x2 u32x2_ma __attribute__((may_alias));

static __device__ __forceinline__ u16_t f2bf(float f) {
    u32_t u = __float_as_uint(f);
    return (u16_t)((u + 0x7FFFu + ((u >> 16) & 1u)) >> 16);
}
static __device__ __forceinline__ u32_t packbf(float a, float b) {
    return (u32_t)f2bf(a) | ((u32_t)f2bf(b) << 16);
}
static __device__ __forceinline__ bf16x8 ld_frag16(const u16_t* p) {
    union { u32x4 u; bf16x8 f; } x;
    x.u = *(const u32x4_ma*)p;
    return x.f;
}
static __device__ __forceinline__ bf16x8 ld_frag32(const u32_t* p) {
    union { u32x4 u; bf16x8 f; } x;
    x.u = *(const u32x4_ma*)p;
    return x.f;
}
static __device__ __forceinline__ bf16x8 asbf(u32x4 u) {
    union { u32x4 u; bf16x8 f; } x;
    x.u = u;
    return x.f;
}

// ---- d_ws table layout (u32 units) ----
#define WSUM_OFF 0        // 512 floats (per-image sigmoid sums)
#define W2R_OFF  512      // 9216 u32: [H][tap][32 ocl][16 icp] packed bf16 pairs
#define WF_OFF   9728     // 3*64 uint4 = 768 u32: conv1 B-frags [s][lane]
#define PT_OFF   10496    // 2560 u32: conv1 A base offsets (u32 units) [tt(40)][lane]
#define BN1_OFF  13056    // 64 u32: 32 x {inv, shift}
#define BN2_OFF  13120    // 128 u32: 64 x {inv, shift}
#define WS_TOTAL 13248    // 52992 B

// crops tile: 36 rows x 37 cols x 4 ch (ch3 = 0), bf16. Pixel = 8 B (2 u32).
// Row pitch = 37*2 = 74 u32. Col 36 is an in-bounds pad (only ever hits kx=3,
// whose weight is 0 -> value irrelevant but must be finite).
#define CI_U32   (36 * 74)                // 2664 u32 = 10656 B
// LDS: 10656 (uniS) + 18496 (hS) + 32 (red) = 29184 B -> wave-capped 4 blocks/CU

// ===== prep: build all block-invariant tables (16 blocks, grid-strided) =====
__global__ __launch_bounds__(512) void prep_kernel(
    const float* __restrict__ w1, const float* __restrict__ b1,
    const float* __restrict__ g1, const float* __restrict__ be1,
    const float* __restrict__ m1, const float* __restrict__ v1,
    const float* __restrict__ w2, const float* __restrict__ b2,
    const float* __restrict__ g2, const float* __restrict__ be2,
    const float* __restrict__ m2, const float* __restrict__ v2,
    u32_t* __restrict__ ws)
{
    const int gtid = blockIdx.x * 512 + threadIdx.x;   // 0..8191

    if (gtid < 512) ws[WSUM_OFF + gtid] = 0u;          // zero wsum[512]

    // w2r: [H][tap][ocl][icp] = packbf(w2[oc][2icp][tap], w2[oc][2icp+1][tap])
    for (int idx = gtid; idx < 9216; idx += 8192) {
        int H   = idx / 4608;
        int rem = idx - H * 4608;
        int tap = rem >> 9;
        int r2  = rem & 511;
        int ocl = r2 >> 4;
        int icp = r2 & 15;
        const float* wp = w2 + (H * 32 + ocl) * 288 + tap;
        ws[W2R_OFF + idx] = packbf(wp[(2 * icp) * 9], wp[(2 * icp + 1) * 9]);
    }
    // wf: conv1 B-frag for (s=ky, lane): k = halfk*8+j; pixel kx = 2*halfk+(j>>2),
    // ch = j&3; value = w1[oc=n32][ch][ky][kx] for kx<3 && ch<3, else 0.
    if (gtid < 192) {
        int s = gtid >> 6, lane = gtid & 63;
        int n32 = lane & 31, h = lane >> 5;
        u32x4 f;
        #pragma unroll
        for (int jp = 0; jp < 4; ++jp) {
            int j0 = 2 * jp, j1 = 2 * jp + 1;
            int kx0 = 2 * h + (j0 >> 2), ch0 = j0 & 3;
            int kx1 = 2 * h + (j1 >> 2), ch1 = j1 & 3;
            float va = (kx0 < 3 && ch0 < 3) ? w1[n32 * 27 + ch0 * 9 + s * 3 + kx0] : 0.f;
            float vb = (kx1 < 3 && ch1 < 3) ? w1[n32 * 27 + ch1 * 9 + s * 3 + kx1] : 0.f;
            f[jp] = packbf(va, vb);
        }
        ((u32x4_ma*)(ws + WF_OFF))[gtid] = f;
    }
    // ptab: conv1 A base offset in u32 units for (tt<40, lane); pA clamped.
    if (gtid < 2560) {
        int tt = gtid >> 6, lane = gtid & 63;
        int n32 = lane & 31, h = lane >> 5;
        int gA = n32 >> 2, sub = n32 & 3;
        int pA = tt * 8 + gA;
        int gy = (pA * 241) >> 12; gy = min(gy, 16);
        int gx = min(pA - gy * 17, 16); gx = max(gx, 0);
        int cy = 2 * gy + (sub >> 1), cx = 2 * gx + (sub & 1);
        ws[PT_OFF + gtid] = (u32_t)((cy * 37 + cx + 2 * h) * 2);
    }
    if (gtid >= 1024 && gtid < 1056) {
        int ch = gtid - 1024;
        float inv = g1[ch] * rsqrtf(v1[ch] + BN_EPS);
        float sh  = b1[ch] * inv + be1[ch] - m1[ch] * inv;
        ws[BN1_OFF + 2 * ch]     = __float_as_uint(inv);
        ws[BN1_OFF + 2 * ch + 1] = __float_as_uint(sh);
    }
    if (gtid >= 2048 && gtid < 2112) {
        int ch = gtid - 2048;
        float inv = g2[ch] * rsqrtf(v2[ch] + BN_EPS);
        float sh  = b2[ch] * inv + be2[ch] - m2[ch] * inv;
        ws[BN2_OFF + 2 * ch]     = __float_as_uint(inv);
        ws[BN2_OFF + 2 * ch + 1] = __float_as_uint(sh);
    }
}

// ============================ fused CNN =====================================
// hS swizzle: logical (group p, ch-chunk c of 4) stored at physical chunk
// c ^ ((p>>1)&3) -> phase-2 lane-stride (2 groups = 128 B = bank period)
// spreads across all 4 chunks => <=2-way (free) instead of 8-way.
__global__ __launch_bounds__(512, 8) void fused_cnn_kernel(
    const float* __restrict__ crops, const u32_t* __restrict__ tab,
    float* __restrict__ out, float* __restrict__ wsum)
{
    __shared__ __align__(16) u32_t uniS[CI_U32];   // crops 4-ch interleaved tile
    __shared__ __align__(16) u16_t hS[289 * 32];   // pooled h (swizzled chunks)
    __shared__ float redS[8];

    const int tid  = threadIdx.x;
    const int wave = tid >> 6;
    const int lane = tid & 63;
    const int quad = lane >> 4;
    const int r    = lane & 15;
    const int n32  = lane & 31;
    const int halfk = lane >> 5;

    const int blk = blockIdx.x;
    const int img = blk >> 4;
    const int t   = blk & 15;
    const int fy0 = (t >> 2) * 4;
    const int fx0 = (t & 3) * 4;
    const int crop_y0 = 8 * fy0 - 3;
    const int crop_x0 = 8 * fx0 - 3;
    const bool interior = (fy0 != 0) && (fx0 != 0);

    // ---- Phase 0: stage crops tile (one b64 write per pixel, ch3 = 0) ----
    const float* cbase = crops + (size_t)img * (3 * HW_ * HW_);
    #pragma unroll
    for (int i = 0; i < 3; ++i) {
        int idx = tid + 512 * i;
        if (idx < 1332) {                          // 36 rows x 37 cols
            int rr = (idx * 1772) >> 16;           // idx/37, exact for idx<1332
            int cc = idx - rr * 37;
            int gr = crop_y0 + rr, gc = crop_x0 + cc;
            float v0 = 0.f, v1v = 0.f, v2v = 0.f;
            if ((unsigned)gr < 128u && (unsigned)gc < 128u) {
                const float* p = cbase + gr * HW_ + gc;
                v0  = p[0];
                v1v = p[HW_ * HW_];
                v2v = p[2 * HW_ * HW_];
            }
            u32x2 w;
            w[0] = packbf(v0, v1v); w[1] = packbf(v2v, 0.f);
            *(u32x2_ma*)&uniS[idx * 2] = w;
        }
    }

    // ---- conv1 B-frags + bn1 from tables ----
    u32x4 wf[3];
    const u32x4_ma* wft = (const u32x4_ma*)(tab + WF_OFF);
    #pragma unroll
    for (int s = 0; s < 3; ++s) wf[s] = wft[s * 64 + lane];
    const float inv1 = __uint_as_float(tab[BN1_OFF + 2 * n32]);
    const float sh1  = __uint_as_float(tab[BN1_OFF + 2 * n32 + 1]);
    __syncthreads();

    // ---- Phase 1: conv1 via 32x32x16 MFMA (3 K-steps), pool in-reg -> hS ----
    const int hsub = n32 & 7;                      // within-chunk ch offset
    const int hchk = n32 >> 3;                     // logical ch-chunk

    #pragma unroll
    for (int i = 0; i < 5; ++i) {                  // uniform 5 trips (tt<40)
        int tt = wave + 8 * i;
        const u32_t* bp = uniS + tab[PT_OFF + tt * 64 + lane];

        // step ky: 16 B at bp + ky*74 u32 (8B-aligned -> ds_read2_b64 pairs)
        u32x2 l0a = *(const u32x2_ma*)(bp);
        u32x2 l0b = *(const u32x2_ma*)(bp + 2);
        u32x2 l1a = *(const u32x2_ma*)(bp + 74);
        u32x2 l1b = *(const u32x2_ma*)(bp + 76);
        u32x2 l2a = *(const u32x2_ma*)(bp + 148);
        u32x2 l2b = *(const u32x2_ma*)(bp + 150);
        u32x4 a0; a0[0] = l0a[0]; a0[1] = l0a[1]; a0[2] = l0b[0]; a0[3] = l0b[1];
        u32x4 a1; a1[0] = l1a[0]; a1[1] = l1a[1]; a1[2] = l1b[0]; a1[3] = l1b[1];
        u32x4 a2; a2[0] = l2a[0]; a2[1] = l2a[1]; a2[2] = l2b[0]; a2[3] = l2b[1];

        f32x16 acc = {0.f,0.f,0.f,0.f,0.f,0.f,0.f,0.f,
                      0.f,0.f,0.f,0.f,0.f,0.f,0.f,0.f};
        acc = __builtin_amdgcn_mfma_f32_32x32x16_bf16(asbf(a0), asbf(wf[0]), acc, 0, 0, 0);
        acc = __builtin_amdgcn_mfma_f32_32x32x16_bf16(asbf(a1), asbf(wf[1]), acc, 0, 0, 0);
        acc = __builtin_amdgcn_mfma_f32_32x32x16_bf16(asbf(a2), asbf(wf[2]), acc, 0, 0, 0);

        // D rows for reg-quad q: pool group pD = tt*8 + 2q + halfk
        #pragma unroll
        for (int q = 0; q < 4; ++q) {
            int pD = tt * 8 + 2 * q + halfk;
            float m4 = fmaxf(fmaxf(acc[4 * q], acc[4 * q + 1]),
                             fmaxf(acc[4 * q + 2], acc[4 * q + 3]));
            float val = fmaxf(fmaf(m4, inv1, sh1), 0.f);
            if (!interior) {          // edge tiles: zero outside global 64x64
                int gyD = (pD * 241) >> 12;
                int gxD = pD - gyD * 17;
                int y2 = 4 * fy0 - 1 + gyD, x2 = 4 * fx0 - 1 + gxD;
                if (y2 < 0 || y2 > 63 || x2 < 0 || x2 > 63) val = 0.f;
            }
            if (pD < 289) {
                int chk = hchk ^ ((pD >> 1) & 3);
                hS[pD * 32 + chk * 8 + hsub] = f2bf(val);
            }
        }
    }
    __syncthreads();   // hS complete

    // ---- Phase 2: conv2, both oc-halves in one pass (shared ah frags) ----
    // A = h positions (lane r), B = weights (global, L1/L2-hot). D: col = oc
    // (constant/lane), rows = 4 subs of pool group 'quad' -> in-reg maxpool.
    float* outp = out + (size_t)img * 16384;
    const f32x4 zero4 = {0.f, 0.f, 0.f, 0.f};
    const int mt  = wave & 1;                      // oc-tile within half
    const int nt0 = wave >> 1;                     // feat row 0..3
    const int cy2 = 2 * nt0 + ((r >> 1) & 1);      // A-side conv-out row
    const int cx2 = 2 * (r >> 2) + (r & 1);        // A-side conv-out col
    const int fy  = fy0 + nt0;

    const u32_t* wz0 = tab + W2R_OFF + (mt * 16 + r) * 16 + quad * 4;
    const u32_t* wz1 = wz0 + 4608;
    f32x4 acc0 = zero4, acc1 = zero4;
    #pragma unroll
    for (int s = 0; s < 9; ++s) {
        const int ky = s / 3, kx = s - 3 * (s / 3);
        int p = (2 * cy2 + ky) * 17 + (2 * cx2 + kx);
        bf16x8 ah = ld_frag16(&hS[p * 32 + ((quad ^ ((p >> 1) & 3)) << 3)]);
        bf16x8 bw0 = ld_frag32(wz0 + s * 512);
        bf16x8 bw1 = ld_frag32(wz1 + s * 512);
        acc0 = __builtin_amdgcn_mfma_f32_16x16x32_bf16(ah, bw0, acc0, 0, 0, 0);
        acc1 = __builtin_amdgcn_mfma_f32_16x16x32_bf16(ah, bw1, acc1, 0, 0, 0);
    }
    float ssum = 0.f;
    #pragma unroll
    for (int H = 0; H < 2; ++H) {
        f32x4 a = H ? acc1 : acc0;
        const int oc = H * 32 + mt * 16 + r;
        const float s2  = __uint_as_float(tab[BN2_OFF + 2 * oc]);
        const float sh2 = __uint_as_float(tab[BN2_OFF + 2 * oc + 1]);
        float m4 = fmaxf(fmaxf(a[0], a[1]), fmaxf(a[2], a[3]));
        float z = fmaf(m4, s2, sh2);
        float sig = 1.f / (1.f + expf(-z));
        outp[oc * 256 + fy * 16 + fx0 + quad] = sig;
        ssum += sig;
    }

    // ---- block score partial -> global atomic ----
    #pragma unroll
    for (int off = 32; off > 0; off >>= 1)
        ssum += __shfl_xor(ssum, off);
    if (lane == 0) redS[wave] = ssum;
    __syncthreads();
    if (tid == 0) {
        float bs = 0.f;
        #pragma unroll
        for (int w = 0; w < 8; ++w) bs += redS[w];
        atomicAdd(&wsum[img], bs);
    }
}

__global__ void finalize_kernel(const float* __restrict__ ws,
                                float* __restrict__ scores,
                                float* __restrict__ detected) {
    int i = threadIdx.x;
    float mean = ws[i] * (1.f / 16384.f);
    scores[i] = mean;
    detected[i] = (mean >= 0.55f) ? 1.f : 0.f;
}

extern "C" void kernel_launch(void* const* d_in, const int* in_sizes, int n_in,
                              void* d_out, int out_size, void* d_ws, size_t ws_size,
                              hipStream_t stream) {
    (void)in_sizes; (void)n_in; (void)out_size; (void)ws_size;
    const float* crops = (const float*)d_in[0];
    const float* w1  = (const float*)d_in[1];
    const float* b1  = (const float*)d_in[2];
    const float* g1  = (const float*)d_in[3];
    const float* be1 = (const float*)d_in[4];
    const float* m1  = (const float*)d_in[5];
    const float* v1  = (const float*)d_in[6];
    const float* w2  = (const float*)d_in[7];
    const float* b2  = (const float*)d_in[8];
    const float* g2  = (const float*)d_in[9];
    const float* be2 = (const float*)d_in[10];
    const float* m2  = (const float*)d_in[11];
    const float* v2  = (const float*)d_in[12];
    float* out = (float*)d_out;
    u32_t* ws  = (u32_t*)d_ws;

    prep_kernel<<<16, 512, 0, stream>>>(
        w1, b1, g1, be1, m1, v1, w2, b2, g2, be2, m2, v2, ws);
    fused_cnn_kernel<<<8192, 512, 0, stream>>>(
        crops, ws, out, (float*)ws);
    finalize_kernel<<<1, 512, 0, stream>>>(
        (const float*)ws, out + 8388608, out + 8388608 + 512);
}